// Round 6
// baseline (408.868 us; speedup 1.0000x reference)
//
#include <hip/hip_runtime.h>
#include <hip/hip_bf16.h>

#define Bb 8
#define Tt 4096
#define Cc 384
#define Hh 6
#define Ee 131072
#define DFF 1536
#define NROWS (Bb * Tt)
#define NEG_SLOPE 0.2f

typedef short bf16x8 __attribute__((ext_vector_type(8)));
typedef float f32x4 __attribute__((ext_vector_type(4)));

__device__ inline float bf2f(unsigned short u) {
    union { unsigned int i; float f; } x; x.i = ((unsigned int)u) << 16; return x.f;
}
__device__ inline unsigned short f2bf(float f) {
    union { float f; unsigned int i; } x; x.f = f;
    unsigned int r = x.i + 0x7fffu + ((x.i >> 16) & 1u);
    return (unsigned short)(r >> 16);
}
__device__ __forceinline__ float blo(unsigned int u) {
    union { unsigned int i; float f; } x; x.i = u << 16; return x.f;
}
__device__ __forceinline__ float bhi(unsigned int u) {
    union { unsigned int i; float f; } x; x.i = u & 0xffff0000u; return x.f;
}

__device__ __forceinline__ void gl_lds16(const unsigned short* g, unsigned short* l) {
    __builtin_amdgcn_global_load_lds(
        (const __attribute__((address_space(1))) unsigned int*)g,
        (__attribute__((address_space(3))) unsigned int*)l,
        16, 0, 0);
}

// ---------------- Wcomb[k][j] = sum_f Wgat[k][hd*64+f] * att[hd][f] ----------------
__global__ void wcomb_kernel(const float* __restrict__ Wgat,
                             const float* __restrict__ att_src,
                             const float* __restrict__ att_dst,
                             float* __restrict__ Wcomb) {
    int t = blockIdx.x * 256 + threadIdx.x;
    if (t >= 384 * 12) return;
    int k = t / 12, j = t % 12;
    int hd = j % 6;
    const float* av = (j < 6 ? att_src : att_dst) + hd * 64;
    const float* wr = Wgat + (size_t)k * Cc + hd * 64;
    float acc = 0.f;
#pragma unroll 8
    for (int f = 0; f < 64; f++) acc = fmaf(wr[f], av[f], acc);
    Wcomb[k * 12 + j] = acc;
}

__device__ __forceinline__ void acc_wcomb(float yq, int c, const float* __restrict__ Wcomb,
                                          float* __restrict__ p) {
    const float4* w = (const float4*)(Wcomb + (size_t)c * 12);
    float4 w0 = w[0], w1 = w[1], w2 = w[2];
    p[0] = fmaf(yq, w0.x, p[0]); p[1] = fmaf(yq, w0.y, p[1]);
    p[2] = fmaf(yq, w0.z, p[2]); p[3] = fmaf(yq, w0.w, p[3]);
    p[4] = fmaf(yq, w1.x, p[4]); p[5] = fmaf(yq, w1.y, p[5]);
    p[6] = fmaf(yq, w1.z, p[6]); p[7] = fmaf(yq, w1.w, p[7]);
    p[8] = fmaf(yq, w2.x, p[8]); p[9] = fmaf(yq, w2.y, p[9]);
    p[10] = fmaf(yq, w2.z, p[10]); p[11] = fmaf(yq, w2.w, p[11]);
}

// ---------------- LN1 -> bf16, fused attention logits: one wave per row ----------------
__global__ __launch_bounds__(256) void ln1_att_kernel(const float* __restrict__ x,
                                                      const float* __restrict__ g,
                                                      const float* __restrict__ b,
                                                      const float* __restrict__ Wcomb,
                                                      unsigned short* __restrict__ y,
                                                      float* __restrict__ asrc,
                                                      float* __restrict__ adst) {
    int row = blockIdx.x * 4 + (threadIdx.x >> 6);
    int lane = threadIdx.x & 63;
    const float* xr = x + (size_t)row * Cc;
    const float4 v4 = *(const float4*)(xr + 4 * lane);
    const float2 v1 = *(const float2*)(xr + 256 + 2 * lane);
    float sum = v4.x + v4.y + v4.z + v4.w + v1.x + v1.y;
    float sq = v4.x * v4.x + v4.y * v4.y + v4.z * v4.z + v4.w * v4.w + v1.x * v1.x + v1.y * v1.y;
#pragma unroll
    for (int off = 1; off < 64; off <<= 1) { sum += __shfl_xor(sum, off); sq += __shfl_xor(sq, off); }
    const float mu = sum * (1.f / 384.f);
    const float var = sq * (1.f / 384.f) - mu * mu;
    const float rs = rsqrtf(var + 1e-5f);
    const float4 g4 = *(const float4*)(g + 4 * lane);
    const float4 b4 = *(const float4*)(b + 4 * lane);
    const float2 g1 = *(const float2*)(g + 256 + 2 * lane);
    const float2 b1 = *(const float2*)(b + 256 + 2 * lane);
    float p[12];
#pragma unroll
    for (int jj = 0; jj < 12; jj++) p[jj] = 0.f;
    const int c4 = 4 * lane, c1 = 256 + 2 * lane;
    const unsigned short u0 = f2bf((v4.x - mu) * rs * g4.x + b4.x);
    const unsigned short u1 = f2bf((v4.y - mu) * rs * g4.y + b4.y);
    const unsigned short u2 = f2bf((v4.z - mu) * rs * g4.z + b4.z);
    const unsigned short u3 = f2bf((v4.w - mu) * rs * g4.w + b4.w);
    const unsigned short u4 = f2bf((v1.x - mu) * rs * g1.x + b1.x);
    const unsigned short u5 = f2bf((v1.y - mu) * rs * g1.y + b1.y);
    acc_wcomb(bf2f(u0), c4 + 0, Wcomb, p);
    acc_wcomb(bf2f(u1), c4 + 1, Wcomb, p);
    acc_wcomb(bf2f(u2), c4 + 2, Wcomb, p);
    acc_wcomb(bf2f(u3), c4 + 3, Wcomb, p);
    acc_wcomb(bf2f(u4), c1 + 0, Wcomb, p);
    acc_wcomb(bf2f(u5), c1 + 1, Wcomb, p);
    unsigned short* yr = y + (size_t)row * Cc;
    uint2 pk4;
    pk4.x = (unsigned int)u0 | ((unsigned int)u1 << 16);
    pk4.y = (unsigned int)u2 | ((unsigned int)u3 << 16);
    *(uint2*)(yr + c4) = pk4;
    *(unsigned int*)(yr + c1) = (unsigned int)u4 | ((unsigned int)u5 << 16);
#pragma unroll
    for (int off = 1; off < 64; off <<= 1)
#pragma unroll
        for (int jj = 0; jj < 12; jj++) p[jj] += __shfl_xor(p[jj], off);
    if (lane == 0) {
        float* as_ = asrc + row * Hh;
        float* ad_ = adst + row * Hh;
        as_[0] = p[0]; as_[1] = p[1]; as_[2] = p[2];
        as_[3] = p[3]; as_[4] = p[4]; as_[5] = p[5];
        ad_[0] = p[6]; ad_[1] = p[7]; ad_[2] = p[8];
        ad_[3] = p[9]; ad_[4] = p[10]; ad_[5] = p[11];
    }
}

// ---------------- W [K][N] f32 -> Wt [N][K] bf16 (32x32 LDS transpose) ----------------
__global__ __launch_bounds__(256) void transpose_bf16_kernel(const float* __restrict__ W,
                                                             unsigned short* __restrict__ Wt,
                                                             int K, int N) {
    __shared__ float t[32][33];
    const int n0 = blockIdx.x * 32, k0 = blockIdx.y * 32;
    const int tx = threadIdx.x & 31, ty = threadIdx.x >> 5;  // 32 x 8
#pragma unroll
    for (int dy = 0; dy < 32; dy += 8)
        t[ty + dy][tx] = W[(size_t)(k0 + ty + dy) * N + n0 + tx];
    __syncthreads();
#pragma unroll
    for (int dy = 0; dy < 32; dy += 8)
        Wt[(size_t)(n0 + ty + dy) * K + k0 + tx] = f2bf(t[tx][ty + dy]);
}

// ---------------- CSR build ----------------
__global__ void count_kernel(const int* __restrict__ dst, int* __restrict__ deg) {
    int e = blockIdx.x * 256 + threadIdx.x;
    if (e < Ee) atomicAdd(&deg[dst[e]], 1);
}

// Wave-level shfl scan (no barriers) + 16-entry cross-wave scan (2 barriers).
__global__ __launch_bounds__(1024) void scan_kernel(int* __restrict__ deg_cursor,
                                                    int* __restrict__ rowptr) {
    __shared__ int wsum[16];
    const int tid = threadIdx.x;
    const int lane = tid & 63;
    const int wv = tid >> 6;
    const int base_i = tid * 4;
    int v[4];
#pragma unroll
    for (int i = 0; i < 4; i++) v[i] = deg_cursor[base_i + i];
    const int s = v[0] + v[1] + v[2] + v[3];
    int incl = s;  // inclusive scan within wave
#pragma unroll
    for (int off = 1; off < 64; off <<= 1) {
        int t = __shfl_up(incl, off);
        if (lane >= off) incl += t;
    }
    if (lane == 63) wsum[wv] = incl;
    __syncthreads();
    if (tid < 16) {
        int ws = wsum[tid];
#pragma unroll
        for (int off = 1; off < 16; off <<= 1) {
            int t = __shfl_up(ws, off, 16);
            if (tid >= off) ws += t;
        }
        wsum[tid] = ws;  // inclusive wave-prefix
    }
    __syncthreads();
    const int wave_excl = (wv == 0) ? 0 : wsum[wv - 1];
    int r = wave_excl + incl - s;  // exclusive prefix for this thread
#pragma unroll
    for (int i = 0; i < 4; i++) { rowptr[base_i + i] = r; deg_cursor[base_i + i] = r; r += v[i]; }
    if (tid == 0) rowptr[Tt] = wsum[15];
}

__global__ void scatter_kernel(const int* __restrict__ src, const int* __restrict__ dst,
                               int* __restrict__ cursor, int* __restrict__ csr) {
    int e = blockIdx.x * 256 + threadIdx.x;
    if (e < Ee) {
        int d = dst[e];
        int pos = atomicAdd(&cursor[d], 1);
        csr[pos] = src[e];
    }
}

// ---------------- GAT aggregation + fused LN2: TWO nodes per wave ----------------
// Proven at 76.9 us (R5): x8 gather batch + __launch_bounds__(256,2).
// XCD-aware batch partitioning: batch = blockIdx.x & 7 (h slice fits XCD L2).
__global__ __launch_bounds__(256, 2) void gat_kernel(const unsigned short* __restrict__ h,
                                                     const float* __restrict__ asrc,
                                                     const float* __restrict__ adst,
                                                     const int* __restrict__ rowptr,
                                                     const int* __restrict__ csr,
                                                     const float* __restrict__ x,
                                                     const float* __restrict__ bgat,
                                                     const float* __restrict__ ln2g,
                                                     const float* __restrict__ ln2b,
                                                     float* __restrict__ x2,
                                                     unsigned short* __restrict__ xn) {
    __shared__ float lds_ex[4][64 * 6];
    const int wave = threadIdx.x >> 6;
    const int lane = threadIdx.x & 63;
    const int batch = blockIdx.x & 7;                 // XCD id (blockIdx%8 round-robin)
    const int pairi = (blockIdx.x >> 3) * 4 + wave;   // within-batch pair index 0..2047
    const int gidA = batch * Tt + pairi * 2;
    const int gidB = gidA + 1;
    const int bt = batch * Tt;
    const int tA = pairi * 2;
    const int halflane = lane & 31;
    const bool isB = lane >= 32;
    const bool hihalf = isB;
    const int wsel = hihalf ? 1 : 0;
    float* exbuf = lds_ex[wave];

    // adst for both nodes (wave-uniform)
    float adA[6], adB[6];
    {
        const float2* pA = (const float2*)(adst + gidA * Hh);
        const float2* pB = (const float2*)(adst + gidB * Hh);
        float2 a0 = pA[0], a1 = pA[1], a2 = pA[2];
        float2 b0 = pB[0], b1 = pB[1], b2 = pB[2];
        adA[0] = a0.x; adA[1] = a0.y; adA[2] = a1.x; adA[3] = a1.y; adA[4] = a2.x; adA[5] = a2.y;
        adB[0] = b0.x; adB[1] = b0.y; adB[2] = b1.x; adB[3] = b1.y; adB[4] = b2.x; adB[5] = b2.y;
    }
    // self-loop exp weights
    float exsA[6], exsB[6];
    {
        const float2* pA = (const float2*)(asrc + gidA * Hh);
        const float2* pB = (const float2*)(asrc + gidB * Hh);
        float2 a0 = pA[0], a1 = pA[1], a2 = pA[2];
        float2 b0 = pB[0], b1 = pB[1], b2 = pB[2];
        float sA[6] = {a0.x, a0.y, a1.x, a1.y, a2.x, a2.y};
        float sB[6] = {b0.x, b0.y, b1.x, b1.y, b2.x, b2.y};
#pragma unroll
        for (int j = 0; j < 6; j++) {
            float a = sA[j] + adA[j];
            a = (a >= 0.f) ? a : NEG_SLOPE * a;
            exsA[j] = __expf(a);
            float c = sB[j] + adB[j];
            c = (c >= 0.f) ? c : NEG_SLOPE * c;
            exsB[j] = __expf(c);
        }
    }
    float den[6];
#pragma unroll
    for (int j = 0; j < 6; j++)
        den[j] = (lane == 0) ? exsA[j] : ((lane == 32) ? exsB[j] : 0.f);

    float accA[3][2], accB[3][2];
    {
        const unsigned short* hA = h + (size_t)gidA * Cc + 2 * lane;
        const unsigned short* hB = h + (size_t)gidB * Cc + 2 * lane;
#pragma unroll
        for (int k = 0; k < 3; k++) {
            unsigned int uA = *(const unsigned int*)(hA + k * 128);
            unsigned int uB = *(const unsigned int*)(hB + k * 128);
            float wA = exsA[2 * k + wsel];
            float wB = exsB[2 * k + wsel];
            accA[k][0] = wA * blo(uA); accA[k][1] = wA * bhi(uA);
            accB[k][0] = wB * blo(uB); accB[k][1] = wB * bhi(uB);
        }
    }

    const int e0A = rowptr[tA], e1A = rowptr[tA + 1], e1B = rowptr[tA + 2];
    const int e0B = e1A;
    const int cntA = e1A - e0A, cntB = e1B - e0B;
    const int maxcnt = cntA > cntB ? cntA : cntB;
    const int my_e0 = isB ? e0B : e0A;
    const int my_e1 = isB ? e1B : e1A;
    float adM[6];
#pragma unroll
    for (int j = 0; j < 6; j++) adM[j] = isB ? adB[j] : adA[j];

    for (int c = 0; c < maxcnt; c += 32) {
        const int e = my_e0 + c + halflane;
        const bool valid = e < my_e1;
        int eidx = valid ? e : (my_e1 - 1);
        eidx = eidx < 0 ? 0 : eidx;
        const int s = csr[eidx];
        const int nb = bt + s;
        float ex[6];
        {
            const float2* ap = (const float2*)(asrc + nb * Hh);
            float2 a01 = ap[0], a23 = ap[1], a45 = ap[2];
            float al[6] = {a01.x, a01.y, a23.x, a23.y, a45.x, a45.y};
#pragma unroll
            for (int j = 0; j < 6; j++) {
                float a = al[j] + adM[j];
                a = (a >= 0.f) ? a : NEG_SLOPE * a;
                float exx = __expf(a);
                ex[j] = valid ? exx : 0.f;
                den[j] += ex[j];
            }
        }
        *(float2*)&exbuf[lane * 6 + 0] = make_float2(ex[0], ex[1]);
        *(float2*)&exbuf[lane * 6 + 2] = make_float2(ex[2], ex[3]);
        *(float2*)&exbuf[lane * 6 + 4] = make_float2(ex[4], ex[5]);

        const int rem = maxcnt - c;
        const int cntc = rem < 32 ? rem : 32;
        int q = 0;
        // x8 batch: 48 dwords in flight (needs the (256,2) VGPR allowance)
        for (; q + 8 <= cntc; q += 8) {
            unsigned int u[8][6];
#pragma unroll
            for (int p = 0; p < 8; p++) {
                const int sbA = __builtin_amdgcn_readlane(s, q + p);
                const int sbB = __builtin_amdgcn_readlane(s, 32 + q + p);
                const unsigned short* hA = h + (size_t)(bt + sbA) * Cc + 2 * lane;
                const unsigned short* hB = h + (size_t)(bt + sbB) * Cc + 2 * lane;
                u[p][0] = *(const unsigned int*)(hA);
                u[p][1] = *(const unsigned int*)(hA + 128);
                u[p][2] = *(const unsigned int*)(hA + 256);
                u[p][3] = *(const unsigned int*)(hB);
                u[p][4] = *(const unsigned int*)(hB + 128);
                u[p][5] = *(const unsigned int*)(hB + 256);
            }
#pragma unroll
            for (int p = 0; p < 8; p++) {
                const int eA = (q + p) * 6 + wsel;
                const int eB = eA + 192;
                const float wA0 = exbuf[eA], wA1 = exbuf[eA + 2], wA2 = exbuf[eA + 4];
                const float wB0 = exbuf[eB], wB1 = exbuf[eB + 2], wB2 = exbuf[eB + 4];
                accA[0][0] = fmaf(wA0, blo(u[p][0]), accA[0][0]);
                accA[0][1] = fmaf(wA0, bhi(u[p][0]), accA[0][1]);
                accA[1][0] = fmaf(wA1, blo(u[p][1]), accA[1][0]);
                accA[1][1] = fmaf(wA1, bhi(u[p][1]), accA[1][1]);
                accA[2][0] = fmaf(wA2, blo(u[p][2]), accA[2][0]);
                accA[2][1] = fmaf(wA2, bhi(u[p][2]), accA[2][1]);
                accB[0][0] = fmaf(wB0, blo(u[p][3]), accB[0][0]);
                accB[0][1] = fmaf(wB0, bhi(u[p][3]), accB[0][1]);
                accB[1][0] = fmaf(wB1, blo(u[p][4]), accB[1][0]);
                accB[1][1] = fmaf(wB1, bhi(u[p][4]), accB[1][1]);
                accB[2][0] = fmaf(wB2, blo(u[p][5]), accB[2][0]);
                accB[2][1] = fmaf(wB2, bhi(u[p][5]), accB[2][1]);
            }
        }
        for (; q + 4 <= cntc; q += 4) {
            unsigned int u[4][6];
#pragma unroll
            for (int p = 0; p < 4; p++) {
                const int sbA = __builtin_amdgcn_readlane(s, q + p);
                const int sbB = __builtin_amdgcn_readlane(s, 32 + q + p);
                const unsigned short* hA = h + (size_t)(bt + sbA) * Cc + 2 * lane;
                const unsigned short* hB = h + (size_t)(bt + sbB) * Cc + 2 * lane;
                u[p][0] = *(const unsigned int*)(hA);
                u[p][1] = *(const unsigned int*)(hA + 128);
                u[p][2] = *(const unsigned int*)(hA + 256);
                u[p][3] = *(const unsigned int*)(hB);
                u[p][4] = *(const unsigned int*)(hB + 128);
                u[p][5] = *(const unsigned int*)(hB + 256);
            }
#pragma unroll
            for (int p = 0; p < 4; p++) {
                const int eA = (q + p) * 6 + wsel;
                const int eB = eA + 192;
                const float wA0 = exbuf[eA], wA1 = exbuf[eA + 2], wA2 = exbuf[eA + 4];
                const float wB0 = exbuf[eB], wB1 = exbuf[eB + 2], wB2 = exbuf[eB + 4];
                accA[0][0] = fmaf(wA0, blo(u[p][0]), accA[0][0]);
                accA[0][1] = fmaf(wA0, bhi(u[p][0]), accA[0][1]);
                accA[1][0] = fmaf(wA1, blo(u[p][1]), accA[1][0]);
                accA[1][1] = fmaf(wA1, bhi(u[p][1]), accA[1][1]);
                accA[2][0] = fmaf(wA2, blo(u[p][2]), accA[2][0]);
                accA[2][1] = fmaf(wA2, bhi(u[p][2]), accA[2][1]);
                accB[0][0] = fmaf(wB0, blo(u[p][3]), accB[0][0]);
                accB[0][1] = fmaf(wB0, bhi(u[p][3]), accB[0][1]);
                accB[1][0] = fmaf(wB1, blo(u[p][4]), accB[1][0]);
                accB[1][1] = fmaf(wB1, bhi(u[p][4]), accB[1][1]);
                accB[2][0] = fmaf(wB2, blo(u[p][5]), accB[2][0]);
                accB[2][1] = fmaf(wB2, bhi(u[p][5]), accB[2][1]);
            }
        }
        for (; q < cntc; q++) {
            const int sbA = __builtin_amdgcn_readlane(s, q);
            const int sbB = __builtin_amdgcn_readlane(s, 32 + q);
            const unsigned short* hA = h + (size_t)(bt + sbA) * Cc + 2 * lane;
            const unsigned short* hB = h + (size_t)(bt + sbB) * Cc + 2 * lane;
            unsigned int u0 = *(const unsigned int*)(hA);
            unsigned int u1 = *(const unsigned int*)(hA + 128);
            unsigned int u2 = *(const unsigned int*)(hA + 256);
            unsigned int u3 = *(const unsigned int*)(hB);
            unsigned int u4 = *(const unsigned int*)(hB + 128);
            unsigned int u5 = *(const unsigned int*)(hB + 256);
            const int eA = q * 6 + wsel;
            const int eB = eA + 192;
            const float wA0 = exbuf[eA], wA1 = exbuf[eA + 2], wA2 = exbuf[eA + 4];
            const float wB0 = exbuf[eB], wB1 = exbuf[eB + 2], wB2 = exbuf[eB + 4];
            accA[0][0] = fmaf(wA0, blo(u0), accA[0][0]);
            accA[0][1] = fmaf(wA0, bhi(u0), accA[0][1]);
            accA[1][0] = fmaf(wA1, blo(u1), accA[1][0]);
            accA[1][1] = fmaf(wA1, bhi(u1), accA[1][1]);
            accA[2][0] = fmaf(wA2, blo(u2), accA[2][0]);
            accA[2][1] = fmaf(wA2, bhi(u2), accA[2][1]);
            accB[0][0] = fmaf(wB0, blo(u3), accB[0][0]);
            accB[0][1] = fmaf(wB0, bhi(u3), accB[0][1]);
            accB[1][0] = fmaf(wB1, blo(u4), accB[1][0]);
            accB[1][1] = fmaf(wB1, bhi(u4), accB[1][1]);
            accB[2][0] = fmaf(wB2, blo(u5), accB[2][0]);
            accB[2][1] = fmaf(wB2, bhi(u5), accB[2][1]);
        }
    }

    // half-wave den reduce (A in lanes 0-31, B in 32-63)
#pragma unroll
    for (int j = 0; j < 6; j++)
#pragma unroll
        for (int off = 1; off < 32; off <<= 1) den[j] += __shfl_xor(den[j], off);
    float denA[6], denB[6];
#pragma unroll
    for (int j = 0; j < 6; j++) { denA[j] = __shfl(den[j], 0); denB[j] = __shfl(den[j], 32); }

    // epilogue for each node: residual x2 + fused LayerNorm2 -> bf16 xn
#pragma unroll
    for (int nd = 0; nd < 2; nd++) {
        const int gid = nd ? gidB : gidA;
        float2 ov[3];
#pragma unroll
        for (int k = 0; k < 3; k++) {
            float d = nd ? denB[2 * k + wsel] : denA[2 * k + wsel];
            float inv = 1.0f / d;
            float a0 = nd ? accB[k][0] : accA[k][0];
            float a1 = nd ? accB[k][1] : accA[k][1];
            const int chan = k * 128 + 2 * lane;
            const size_t idx = (size_t)gid * Cc + chan;
            const float2 bg = *(const float2*)(bgat + chan);
            const float2 xv = *(const float2*)(x + idx);
            ov[k].x = fmaf(a0, inv, bg.x + xv.x);
            ov[k].y = fmaf(a1, inv, bg.y + xv.y);
            *(float2*)(x2 + idx) = ov[k];
        }
        float sum = 0.f, sq = 0.f;
#pragma unroll
        for (int k = 0; k < 3; k++) {
            sum += ov[k].x + ov[k].y;
            sq += ov[k].x * ov[k].x + ov[k].y * ov[k].y;
        }
#pragma unroll
        for (int off = 1; off < 64; off <<= 1) { sum += __shfl_xor(sum, off); sq += __shfl_xor(sq, off); }
        const float mu = sum * (1.f / 384.f);
        const float var = sq * (1.f / 384.f) - mu * mu;
        const float rs = rsqrtf(var + 1e-5f);
#pragma unroll
        for (int k = 0; k < 3; k++) {
            const int chan = k * 128 + 2 * lane;
            const size_t idx = (size_t)gid * Cc + chan;
            const float2 gg = *(const float2*)(ln2g + chan);
            const float2 bb = *(const float2*)(ln2b + chan);
            float y0 = (ov[k].x - mu) * rs * gg.x + bb.x;
            float y1 = (ov[k].y - mu) * rs * gg.y + bb.y;
            unsigned int pack = (unsigned int)f2bf(y0) | ((unsigned int)f2bf(y1) << 16);
            *(unsigned int*)(xn + idx) = pack;
        }
    }
}

// ---------------- MFMA bf16 GEMM: C[M,N] = A[M,K] @ Bt[N,K]^T ----------------
// BM=256 x BN=128 tile, 8 waves (4x2), wave tile 64x64 (4x4 of 16x16x32 MFMA),
// BK=64 as two BK=32 LDS sub-panels, global_load_lds width-16 staging.
// vs the 128x128/4-wave version: staged bytes per wave-MFMA 256->192 B (B-panel
// amortized over 2x M-rows), half the blocks (fewer prologue/epilogues).
// LDS 64 KB -> 2 blocks/CU; __launch_bounds__(512,4) pins VGPR<=128 so 16
// waves/CU hold. Per-wave MFMA/LDS-read/epilogue pattern identical to proven kernel.
// EPI: 1 = +bias, relu, store bf16; 2 = +bias +resid, store f32; 3 = store bf16
template <int EPI>
__global__ __launch_bounds__(512, 4) void mfma_gemm(const unsigned short* __restrict__ A,
                                                    const unsigned short* __restrict__ Bt,
                                                    const float* __restrict__ bias,
                                                    const float* __restrict__ resid,
                                                    void* __restrict__ Cout,
                                                    int M, int N, int K) {
    __shared__ unsigned short lds_buf[32768];  // 64 KB: staging (48 KB) + epilogue (64 KB)
    unsigned short* Als = lds_buf;             // 2 subpanels x [256][32]
    unsigned short* Bls = lds_buf + 16384;     // 2 subpanels x [128][32]
    const int tid = threadIdx.x;
    const int wave = tid >> 6, lane = tid & 63;
    const int quad = lane >> 4, l16 = lane & 15;
    const int wm = (wave >> 1) * 64, wn = (wave & 1) * 64;
    const int bm = blockIdx.y, bn = blockIdx.x;

    const int rowin = lane >> 2;     // 0..15
    const int kel = (lane & 3) * 8;  // 0,8,16,24

    // wave w stages A rows [32w,32w+32) (2 loads x 2 subpanels) and B rows [16w,16w+16)
    const unsigned short* ga = A + (size_t)(bm * 256 + wave * 32 + rowin) * K + kel;
    const unsigned short* gb = Bt + (size_t)(bn * 128 + wave * 16 + rowin) * K + kel;
    unsigned short* la = Als + wave * 1024;
    unsigned short* lb = Bls + wave * 512;

    f32x4 acc[4][4] = {};

    for (int k0 = 0; k0 < K; k0 += 64) {
        gl_lds16(ga + k0, la);
        gl_lds16(ga + k0 + (size_t)16 * K, la + 512);
        gl_lds16(ga + k0 + 32, la + 8192);
        gl_lds16(ga + k0 + (size_t)16 * K + 32, la + 8192 + 512);
        gl_lds16(gb + k0, lb);
        gl_lds16(gb + k0 + 32, lb + 4096);
        __syncthreads();
#pragma unroll
        for (int hh = 0; hh < 2; hh++) {
            bf16x8 af[4], bfr[4];
#pragma unroll
            for (int i = 0; i < 4; i++) {
                af[i]  = *(const bf16x8*)(Als + hh * 8192 + (wm + i * 16 + l16) * 32 + quad * 8);
                bfr[i] = *(const bf16x8*)(Bls + hh * 4096 + (wn + i * 16 + l16) * 32 + quad * 8);
            }
#pragma unroll
            for (int i = 0; i < 4; i++)
#pragma unroll
                for (int j = 0; j < 4; j++)
                    acc[i][j] = __builtin_amdgcn_mfma_f32_16x16x32_bf16(af[i], bfr[j], acc[i][j], 0, 0, 0);
        }
        __syncthreads();
    }

    // -------- epilogue: wave-local 64x64 LDS transpose -> coalesced stores --------
    const int gr0 = bm * 256 + wm;
    const int gc0 = bn * 128 + wn;

    if constexpr (EPI == 1 || EPI == 3) {
        // bf16 output: wave tile [64][64] shorts = 8 KB/wave, 16B-chunk swizzle chunk^(row&7)
        unsigned short* ep = lds_buf + wave * 4096;
#pragma unroll
        for (int i = 0; i < 4; i++) {
#pragma unroll
            for (int j = 0; j < 4; j++) {
                const int cl = j * 16 + l16;
                const float bv = (EPI == 1) ? bias[gc0 + cl] : 0.f;
#pragma unroll
                for (int r = 0; r < 4; r++) {
                    const int rl = i * 16 + quad * 4 + r;
                    float v = acc[i][j][r] + bv;
                    if constexpr (EPI == 1) v = fmaxf(v, 0.f);
                    ep[rl * 64 + (((cl >> 3) ^ (rl & 7)) << 3) + (cl & 7)] = f2bf(v);
                }
            }
        }
        __syncthreads();
        unsigned short* co = (unsigned short*)Cout;
#pragma unroll
        for (int c = 0; c < 8; c++) {
            const int rl = c * 8 + (lane >> 3);
            const int ch = (lane & 7) ^ (rl & 7);
            bf16x8 vv = *(const bf16x8*)(ep + rl * 64 + ch * 8);
            *(bf16x8*)(co + (size_t)(gr0 + rl) * N + gc0 + (lane & 7) * 8) = vv;
        }
    } else {
        // EPI == 2: f32 output + resid. Two half-passes of [32][64] f32 = 8 KB/wave,
        // 16B-chunk swizzle chunk^(row&15); float4 resid loads + f32x4 stores.
        float* epf = (float*)lds_buf + wave * 2048;
        float* co = (float*)Cout;
#pragma unroll
        for (int hp = 0; hp < 2; hp++) {
            if (hp) __syncthreads();
#pragma unroll
            for (int i2 = 0; i2 < 2; i2++) {
                const int i = hp * 2 + i2;
#pragma unroll
                for (int j = 0; j < 4; j++) {
                    const int cl = j * 16 + l16;
                    const float bv = bias[gc0 + cl];
#pragma unroll
                    for (int r = 0; r < 4; r++) {
                        const int rl = i2 * 16 + quad * 4 + r;
                        epf[rl * 64 + (((cl >> 2) ^ (rl & 15)) << 2) + (cl & 3)] = acc[i][j][r] + bv;
                    }
                }
            }
            __syncthreads();
#pragma unroll
            for (int c = 0; c < 8; c++) {
                const int rl = c * 4 + (lane >> 4);
                const int ch = (lane & 15) ^ (rl & 15);
                f32x4 vv = *(const f32x4*)(epf + rl * 64 + ch * 4);
                const size_t gidx = (size_t)(gr0 + hp * 32 + rl) * N + gc0 + (lane & 15) * 4;
                const f32x4 rr = *(const f32x4*)(resid + gidx);
                vv += rr;
                *(f32x4*)(co + gidx) = vv;
            }
        }
    }
}

extern "C" void kernel_launch(void* const* d_in, const int* in_sizes, int n_in,
                              void* d_out, int out_size, void* d_ws, size_t ws_size,
                              hipStream_t stream) {
    (void)in_sizes; (void)n_in; (void)out_size; (void)ws_size;
    const float* x      = (const float*)d_in[0];
    const int*   ei     = (const int*)d_in[1];
    const float* Wgat   = (const float*)d_in[2];
    const float* attsrc = (const float*)d_in[3];
    const float* attdst = (const float*)d_in[4];
    const float* bgat   = (const float*)d_in[5];
    const float* ln1g   = (const float*)d_in[6];
    const float* ln1b   = (const float*)d_in[7];
    const float* ln2g   = (const float*)d_in[8];
    const float* ln2b   = (const float*)d_in[9];
    const float* W1     = (const float*)d_in[10];
    const float* b1     = (const float*)d_in[11];
    const float* W2     = (const float*)d_in[12];
    const float* b2     = (const float*)d_in[13];
    float* out = (float*)d_out;

    const int* srcp = ei;
    const int* dstp = ei + Ee;

    // workspace layout (all chunks 16B-aligned by construction)
    char* p = (char*)d_ws;
    unsigned short* xn = (unsigned short*)p; p += (size_t)NROWS * Cc * 2;        // LN out, bf16
    unsigned short* h = (unsigned short*)p; p += (size_t)NROWS * Cc * 2;          // GAT features, bf16
    float* asrc = (float*)p; p += (size_t)NROWS * Hh * 4;
    float* adst = (float*)p; p += (size_t)NROWS * Hh * 4;
    unsigned short* ffn1 = (unsigned short*)p; p += (size_t)NROWS * DFF * 2;      // bf16
    unsigned short* wgt = (unsigned short*)p; p += (size_t)Cc * Cc * 2;           // W_gat^T bf16
    unsigned short* w1t = (unsigned short*)p; p += (size_t)DFF * Cc * 2;          // W1^T bf16
    unsigned short* w2t = (unsigned short*)p; p += (size_t)Cc * DFF * 2;          // W2^T bf16
    float* wcomb = (float*)p; p += (size_t)Cc * 12 * 4;                            // folded att weights
    int* rowptr = (int*)p; p += (Tt + 1) * 4;
    int* cursor = (int*)p; p += Tt * 4;
    int* csr = (int*)p; p += (size_t)Ee * 4;

    // weight convert+transpose + folded attention weights (once per launch, tiny)
    transpose_bf16_kernel<<<dim3(Cc / 32, Cc / 32), 256, 0, stream>>>(Wgat, wgt, Cc, Cc);
    transpose_bf16_kernel<<<dim3(DFF / 32, Cc / 32), 256, 0, stream>>>(W1, w1t, Cc, DFF);
    transpose_bf16_kernel<<<dim3(Cc / 32, DFF / 32), 256, 0, stream>>>(W2, w2t, DFF, Cc);
    wcomb_kernel<<<18, 256, 0, stream>>>(Wgat, attsrc, attdst, wcomb);

    // CSR build (batch-independent)
    hipMemsetAsync(cursor, 0, Tt * sizeof(int), stream);
    count_kernel<<<(Ee + 255) / 256, 256, 0, stream>>>(dstp, cursor);
    scan_kernel<<<1, 1024, 0, stream>>>(cursor, rowptr);
    scatter_kernel<<<(Ee + 255) / 256, 256, 0, stream>>>(srcp, dstp, cursor, csr);

    // LN1 -> bf16 xn, fused asrc/adst
    ln1_att_kernel<<<NROWS / 4, 256, 0, stream>>>(x, ln1g, ln1b, wcomb, xn, asrc, adst);
    // h = xn @ W_gat  (bf16 out)
    mfma_gemm<3><<<dim3(Cc / 128, NROWS / 256), 512, 0, stream>>>(
        xn, wgt, nullptr, nullptr, h, NROWS, Cc, Cc);
    // GAT aggregation + bias + residual -> out, fused LN2 -> xn (bf16)
    gat_kernel<<<NROWS / 8, 256, 0, stream>>>(h, asrc, adst, rowptr, csr, x, bgat,
                                              ln2g, ln2b, out, xn);
    // ffn1 = relu(xn @ W1 + b1) -> bf16
    mfma_gemm<1><<<dim3(DFF / 128, NROWS / 256), 512, 0, stream>>>(
        xn, w1t, b1, nullptr, ffn1, NROWS, DFF, Cc);
    // out = ffn1 @ W2 + b2 + out
    mfma_gemm<2><<<dim3(Cc / 128, NROWS / 256), 512, 0, stream>>>(
        ffn1, w2t, b2, out, out, NROWS, Cc, DFF);
}

// Round 7
// 403.146 us; speedup vs baseline: 1.0142x; 1.0142x over previous
//
#include <hip/hip_runtime.h>
#include <hip/hip_bf16.h>

#define Bb 8
#define Tt 4096
#define Cc 384
#define Hh 6
#define Ee 131072
#define DFF 1536
#define NROWS (Bb * Tt)
#define NEG_SLOPE 0.2f

typedef short bf16x8 __attribute__((ext_vector_type(8)));
typedef float f32x4 __attribute__((ext_vector_type(4)));

__device__ inline float bf2f(unsigned short u) {
    union { unsigned int i; float f; } x; x.i = ((unsigned int)u) << 16; return x.f;
}
__device__ inline unsigned short f2bf(float f) {
    union { float f; unsigned int i; } x; x.f = f;
    unsigned int r = x.i + 0x7fffu + ((x.i >> 16) & 1u);
    return (unsigned short)(r >> 16);
}
__device__ __forceinline__ float blo(unsigned int u) {
    union { unsigned int i; float f; } x; x.i = u << 16; return x.f;
}
__device__ __forceinline__ float bhi(unsigned int u) {
    union { unsigned int i; float f; } x; x.i = u & 0xffff0000u; return x.f;
}

__device__ __forceinline__ void gl_lds16(const unsigned short* g, unsigned short* l) {
    __builtin_amdgcn_global_load_lds(
        (const __attribute__((address_space(1))) unsigned int*)g,
        (__attribute__((address_space(3))) unsigned int*)l,
        16, 0, 0);
}

// ---------------- Wcomb[k][j] = sum_f Wgat[k][hd*64+f] * att[hd][f] ----------------
__global__ void wcomb_kernel(const float* __restrict__ Wgat,
                             const float* __restrict__ att_src,
                             const float* __restrict__ att_dst,
                             float* __restrict__ Wcomb) {
    int t = blockIdx.x * 256 + threadIdx.x;
    if (t >= 384 * 12) return;
    int k = t / 12, j = t % 12;
    int hd = j % 6;
    const float* av = (j < 6 ? att_src : att_dst) + hd * 64;
    const float* wr = Wgat + (size_t)k * Cc + hd * 64;
    float acc = 0.f;
#pragma unroll 8
    for (int f = 0; f < 64; f++) acc = fmaf(wr[f], av[f], acc);
    Wcomb[k * 12 + j] = acc;
}

__device__ __forceinline__ void acc_wcomb(float yq, int c, const float* __restrict__ Wcomb,
                                          float* __restrict__ p) {
    const float4* w = (const float4*)(Wcomb + (size_t)c * 12);
    float4 w0 = w[0], w1 = w[1], w2 = w[2];
    p[0] = fmaf(yq, w0.x, p[0]); p[1] = fmaf(yq, w0.y, p[1]);
    p[2] = fmaf(yq, w0.z, p[2]); p[3] = fmaf(yq, w0.w, p[3]);
    p[4] = fmaf(yq, w1.x, p[4]); p[5] = fmaf(yq, w1.y, p[5]);
    p[6] = fmaf(yq, w1.z, p[6]); p[7] = fmaf(yq, w1.w, p[7]);
    p[8] = fmaf(yq, w2.x, p[8]); p[9] = fmaf(yq, w2.y, p[9]);
    p[10] = fmaf(yq, w2.z, p[10]); p[11] = fmaf(yq, w2.w, p[11]);
}

// ---------------- LN1 -> bf16, fused attention logits: one wave per row ----------------
__global__ __launch_bounds__(256) void ln1_att_kernel(const float* __restrict__ x,
                                                      const float* __restrict__ g,
                                                      const float* __restrict__ b,
                                                      const float* __restrict__ Wcomb,
                                                      unsigned short* __restrict__ y,
                                                      float* __restrict__ asrc,
                                                      float* __restrict__ adst) {
    int row = blockIdx.x * 4 + (threadIdx.x >> 6);
    int lane = threadIdx.x & 63;
    const float* xr = x + (size_t)row * Cc;
    const float4 v4 = *(const float4*)(xr + 4 * lane);
    const float2 v1 = *(const float2*)(xr + 256 + 2 * lane);
    float sum = v4.x + v4.y + v4.z + v4.w + v1.x + v1.y;
    float sq = v4.x * v4.x + v4.y * v4.y + v4.z * v4.z + v4.w * v4.w + v1.x * v1.x + v1.y * v1.y;
#pragma unroll
    for (int off = 1; off < 64; off <<= 1) { sum += __shfl_xor(sum, off); sq += __shfl_xor(sq, off); }
    const float mu = sum * (1.f / 384.f);
    const float var = sq * (1.f / 384.f) - mu * mu;
    const float rs = rsqrtf(var + 1e-5f);
    const float4 g4 = *(const float4*)(g + 4 * lane);
    const float4 b4 = *(const float4*)(b + 4 * lane);
    const float2 g1 = *(const float2*)(g + 256 + 2 * lane);
    const float2 b1 = *(const float2*)(b + 256 + 2 * lane);
    float p[12];
#pragma unroll
    for (int jj = 0; jj < 12; jj++) p[jj] = 0.f;
    const int c4 = 4 * lane, c1 = 256 + 2 * lane;
    const unsigned short u0 = f2bf((v4.x - mu) * rs * g4.x + b4.x);
    const unsigned short u1 = f2bf((v4.y - mu) * rs * g4.y + b4.y);
    const unsigned short u2 = f2bf((v4.z - mu) * rs * g4.z + b4.z);
    const unsigned short u3 = f2bf((v4.w - mu) * rs * g4.w + b4.w);
    const unsigned short u4 = f2bf((v1.x - mu) * rs * g1.x + b1.x);
    const unsigned short u5 = f2bf((v1.y - mu) * rs * g1.y + b1.y);
    acc_wcomb(bf2f(u0), c4 + 0, Wcomb, p);
    acc_wcomb(bf2f(u1), c4 + 1, Wcomb, p);
    acc_wcomb(bf2f(u2), c4 + 2, Wcomb, p);
    acc_wcomb(bf2f(u3), c4 + 3, Wcomb, p);
    acc_wcomb(bf2f(u4), c1 + 0, Wcomb, p);
    acc_wcomb(bf2f(u5), c1 + 1, Wcomb, p);
    unsigned short* yr = y + (size_t)row * Cc;
    uint2 pk4;
    pk4.x = (unsigned int)u0 | ((unsigned int)u1 << 16);
    pk4.y = (unsigned int)u2 | ((unsigned int)u3 << 16);
    *(uint2*)(yr + c4) = pk4;
    *(unsigned int*)(yr + c1) = (unsigned int)u4 | ((unsigned int)u5 << 16);
#pragma unroll
    for (int off = 1; off < 64; off <<= 1)
#pragma unroll
        for (int jj = 0; jj < 12; jj++) p[jj] += __shfl_xor(p[jj], off);
    if (lane == 0) {
        float* as_ = asrc + row * Hh;
        float* ad_ = adst + row * Hh;
        as_[0] = p[0]; as_[1] = p[1]; as_[2] = p[2];
        as_[3] = p[3]; as_[4] = p[4]; as_[5] = p[5];
        ad_[0] = p[6]; ad_[1] = p[7]; ad_[2] = p[8];
        ad_[3] = p[9]; ad_[4] = p[10]; ad_[5] = p[11];
    }
}

// ---------------- W [K][N] f32 -> Wt [N][K] bf16 (32x32 LDS transpose) ----------------
__global__ __launch_bounds__(256) void transpose_bf16_kernel(const float* __restrict__ W,
                                                             unsigned short* __restrict__ Wt,
                                                             int K, int N) {
    __shared__ float t[32][33];
    const int n0 = blockIdx.x * 32, k0 = blockIdx.y * 32;
    const int tx = threadIdx.x & 31, ty = threadIdx.x >> 5;  // 32 x 8
#pragma unroll
    for (int dy = 0; dy < 32; dy += 8)
        t[ty + dy][tx] = W[(size_t)(k0 + ty + dy) * N + n0 + tx];
    __syncthreads();
#pragma unroll
    for (int dy = 0; dy < 32; dy += 8)
        Wt[(size_t)(n0 + ty + dy) * K + k0 + tx] = f2bf(t[tx][ty + dy]);
}

// ---------------- CSR build ----------------
__global__ void count_kernel(const int* __restrict__ dst, int* __restrict__ deg) {
    int e = blockIdx.x * 256 + threadIdx.x;
    if (e < Ee) atomicAdd(&deg[dst[e]], 1);
}

// Wave-level shfl scan (no barriers) + 16-entry cross-wave scan (2 barriers).
__global__ __launch_bounds__(1024) void scan_kernel(int* __restrict__ deg_cursor,
                                                    int* __restrict__ rowptr) {
    __shared__ int wsum[16];
    const int tid = threadIdx.x;
    const int lane = tid & 63;
    const int wv = tid >> 6;
    const int base_i = tid * 4;
    int v[4];
#pragma unroll
    for (int i = 0; i < 4; i++) v[i] = deg_cursor[base_i + i];
    const int s = v[0] + v[1] + v[2] + v[3];
    int incl = s;  // inclusive scan within wave
#pragma unroll
    for (int off = 1; off < 64; off <<= 1) {
        int t = __shfl_up(incl, off);
        if (lane >= off) incl += t;
    }
    if (lane == 63) wsum[wv] = incl;
    __syncthreads();
    if (tid < 16) {
        int ws = wsum[tid];
#pragma unroll
        for (int off = 1; off < 16; off <<= 1) {
            int t = __shfl_up(ws, off, 16);
            if (tid >= off) ws += t;
        }
        wsum[tid] = ws;  // inclusive wave-prefix
    }
    __syncthreads();
    const int wave_excl = (wv == 0) ? 0 : wsum[wv - 1];
    int r = wave_excl + incl - s;  // exclusive prefix for this thread
#pragma unroll
    for (int i = 0; i < 4; i++) { rowptr[base_i + i] = r; deg_cursor[base_i + i] = r; r += v[i]; }
    if (tid == 0) rowptr[Tt] = wsum[15];
}

__global__ void scatter_kernel(const int* __restrict__ src, const int* __restrict__ dst,
                               int* __restrict__ cursor, int* __restrict__ csr) {
    int e = blockIdx.x * 256 + threadIdx.x;
    if (e < Ee) {
        int d = dst[e];
        int pos = atomicAdd(&cursor[d], 1);
        csr[pos] = src[e];
    }
}

// ---------------- GAT aggregation + fused LN2: TWO nodes per wave ----------------
// R5 structure (x8 gather batch, 76.9 us) + waves_per_eu(2,3): caps the
// occupancy TARGET at 3 waves/EU (= the measured ~34% anyway), raising the
// per-wave VGPR budget to ~170 so the 48-dword x8 batch can be fully live
// (R3/R5 trend: VGPR 48 -> 93-179us, 64 -> 77us; allocator kept splitting
// the batch). XCD-aware batch partitioning: batch = blockIdx.x & 7.
__global__ __launch_bounds__(256)
__attribute__((amdgpu_waves_per_eu(2, 3)))
void gat_kernel(const unsigned short* __restrict__ h,
                const float* __restrict__ asrc,
                const float* __restrict__ adst,
                const int* __restrict__ rowptr,
                const int* __restrict__ csr,
                const float* __restrict__ x,
                const float* __restrict__ bgat,
                const float* __restrict__ ln2g,
                const float* __restrict__ ln2b,
                float* __restrict__ x2,
                unsigned short* __restrict__ xn) {
    __shared__ float lds_ex[4][64 * 6];
    const int wave = threadIdx.x >> 6;
    const int lane = threadIdx.x & 63;
    const int batch = blockIdx.x & 7;                 // XCD id (blockIdx%8 round-robin)
    const int pairi = (blockIdx.x >> 3) * 4 + wave;   // within-batch pair index 0..2047
    const int gidA = batch * Tt + pairi * 2;
    const int gidB = gidA + 1;
    const int bt = batch * Tt;
    const int tA = pairi * 2;
    const int halflane = lane & 31;
    const bool isB = lane >= 32;
    const bool hihalf = isB;
    const int wsel = hihalf ? 1 : 0;
    float* exbuf = lds_ex[wave];

    // adst for both nodes (wave-uniform)
    float adA[6], adB[6];
    {
        const float2* pA = (const float2*)(adst + gidA * Hh);
        const float2* pB = (const float2*)(adst + gidB * Hh);
        float2 a0 = pA[0], a1 = pA[1], a2 = pA[2];
        float2 b0 = pB[0], b1 = pB[1], b2 = pB[2];
        adA[0] = a0.x; adA[1] = a0.y; adA[2] = a1.x; adA[3] = a1.y; adA[4] = a2.x; adA[5] = a2.y;
        adB[0] = b0.x; adB[1] = b0.y; adB[2] = b1.x; adB[3] = b1.y; adB[4] = b2.x; adB[5] = b2.y;
    }
    // self-loop exp weights
    float exsA[6], exsB[6];
    {
        const float2* pA = (const float2*)(asrc + gidA * Hh);
        const float2* pB = (const float2*)(asrc + gidB * Hh);
        float2 a0 = pA[0], a1 = pA[1], a2 = pA[2];
        float2 b0 = pB[0], b1 = pB[1], b2 = pB[2];
        float sA[6] = {a0.x, a0.y, a1.x, a1.y, a2.x, a2.y};
        float sB[6] = {b0.x, b0.y, b1.x, b1.y, b2.x, b2.y};
#pragma unroll
        for (int j = 0; j < 6; j++) {
            float a = sA[j] + adA[j];
            a = (a >= 0.f) ? a : NEG_SLOPE * a;
            exsA[j] = __expf(a);
            float c = sB[j] + adB[j];
            c = (c >= 0.f) ? c : NEG_SLOPE * c;
            exsB[j] = __expf(c);
        }
    }
    float den[6];
#pragma unroll
    for (int j = 0; j < 6; j++)
        den[j] = (lane == 0) ? exsA[j] : ((lane == 32) ? exsB[j] : 0.f);

    float accA[3][2], accB[3][2];
    {
        const unsigned short* hA = h + (size_t)gidA * Cc + 2 * lane;
        const unsigned short* hB = h + (size_t)gidB * Cc + 2 * lane;
#pragma unroll
        for (int k = 0; k < 3; k++) {
            unsigned int uA = *(const unsigned int*)(hA + k * 128);
            unsigned int uB = *(const unsigned int*)(hB + k * 128);
            float wA = exsA[2 * k + wsel];
            float wB = exsB[2 * k + wsel];
            accA[k][0] = wA * blo(uA); accA[k][1] = wA * bhi(uA);
            accB[k][0] = wB * blo(uB); accB[k][1] = wB * bhi(uB);
        }
    }

    const int e0A = rowptr[tA], e1A = rowptr[tA + 1], e1B = rowptr[tA + 2];
    const int e0B = e1A;
    const int cntA = e1A - e0A, cntB = e1B - e0B;
    const int maxcnt = cntA > cntB ? cntA : cntB;
    const int my_e0 = isB ? e0B : e0A;
    const int my_e1 = isB ? e1B : e1A;
    float adM[6];
#pragma unroll
    for (int j = 0; j < 6; j++) adM[j] = isB ? adB[j] : adA[j];

    for (int c = 0; c < maxcnt; c += 32) {
        const int e = my_e0 + c + halflane;
        const bool valid = e < my_e1;
        int eidx = valid ? e : (my_e1 - 1);
        eidx = eidx < 0 ? 0 : eidx;
        const int s = csr[eidx];
        const int nb = bt + s;
        float ex[6];
        {
            const float2* ap = (const float2*)(asrc + nb * Hh);
            float2 a01 = ap[0], a23 = ap[1], a45 = ap[2];
            float al[6] = {a01.x, a01.y, a23.x, a23.y, a45.x, a45.y};
#pragma unroll
            for (int j = 0; j < 6; j++) {
                float a = al[j] + adM[j];
                a = (a >= 0.f) ? a : NEG_SLOPE * a;
                float exx = __expf(a);
                ex[j] = valid ? exx : 0.f;
                den[j] += ex[j];
            }
        }
        *(float2*)&exbuf[lane * 6 + 0] = make_float2(ex[0], ex[1]);
        *(float2*)&exbuf[lane * 6 + 2] = make_float2(ex[2], ex[3]);
        *(float2*)&exbuf[lane * 6 + 4] = make_float2(ex[4], ex[5]);

        const int rem = maxcnt - c;
        const int cntc = rem < 32 ? rem : 32;
        int q = 0;
        // x8 batch: 48 dwords in flight
        for (; q + 8 <= cntc; q += 8) {
            unsigned int u[8][6];
#pragma unroll
            for (int p = 0; p < 8; p++) {
                const int sbA = __builtin_amdgcn_readlane(s, q + p);
                const int sbB = __builtin_amdgcn_readlane(s, 32 + q + p);
                const unsigned short* hA = h + (size_t)(bt + sbA) * Cc + 2 * lane;
                const unsigned short* hB = h + (size_t)(bt + sbB) * Cc + 2 * lane;
                u[p][0] = *(const unsigned int*)(hA);
                u[p][1] = *(const unsigned int*)(hA + 128);
                u[p][2] = *(const unsigned int*)(hA + 256);
                u[p][3] = *(const unsigned int*)(hB);
                u[p][4] = *(const unsigned int*)(hB + 128);
                u[p][5] = *(const unsigned int*)(hB + 256);
            }
#pragma unroll
            for (int p = 0; p < 8; p++) {
                const int eA = (q + p) * 6 + wsel;
                const int eB = eA + 192;
                const float wA0 = exbuf[eA], wA1 = exbuf[eA + 2], wA2 = exbuf[eA + 4];
                const float wB0 = exbuf[eB], wB1 = exbuf[eB + 2], wB2 = exbuf[eB + 4];
                accA[0][0] = fmaf(wA0, blo(u[p][0]), accA[0][0]);
                accA[0][1] = fmaf(wA0, bhi(u[p][0]), accA[0][1]);
                accA[1][0] = fmaf(wA1, blo(u[p][1]), accA[1][0]);
                accA[1][1] = fmaf(wA1, bhi(u[p][1]), accA[1][1]);
                accA[2][0] = fmaf(wA2, blo(u[p][2]), accA[2][0]);
                accA[2][1] = fmaf(wA2, bhi(u[p][2]), accA[2][1]);
                accB[0][0] = fmaf(wB0, blo(u[p][3]), accB[0][0]);
                accB[0][1] = fmaf(wB0, bhi(u[p][3]), accB[0][1]);
                accB[1][0] = fmaf(wB1, blo(u[p][4]), accB[1][0]);
                accB[1][1] = fmaf(wB1, bhi(u[p][4]), accB[1][1]);
                accB[2][0] = fmaf(wB2, blo(u[p][5]), accB[2][0]);
                accB[2][1] = fmaf(wB2, bhi(u[p][5]), accB[2][1]);
            }
        }
        for (; q + 4 <= cntc; q += 4) {
            unsigned int u[4][6];
#pragma unroll
            for (int p = 0; p < 4; p++) {
                const int sbA = __builtin_amdgcn_readlane(s, q + p);
                const int sbB = __builtin_amdgcn_readlane(s, 32 + q + p);
                const unsigned short* hA = h + (size_t)(bt + sbA) * Cc + 2 * lane;
                const unsigned short* hB = h + (size_t)(bt + sbB) * Cc + 2 * lane;
                u[p][0] = *(const unsigned int*)(hA);
                u[p][1] = *(const unsigned int*)(hA + 128);
                u[p][2] = *(const unsigned int*)(hA + 256);
                u[p][3] = *(const unsigned int*)(hB);
                u[p][4] = *(const unsigned int*)(hB + 128);
                u[p][5] = *(const unsigned int*)(hB + 256);
            }
#pragma unroll
            for (int p = 0; p < 4; p++) {
                const int eA = (q + p) * 6 + wsel;
                const int eB = eA + 192;
                const float wA0 = exbuf[eA], wA1 = exbuf[eA + 2], wA2 = exbuf[eA + 4];
                const float wB0 = exbuf[eB], wB1 = exbuf[eB + 2], wB2 = exbuf[eB + 4];
                accA[0][0] = fmaf(wA0, blo(u[p][0]), accA[0][0]);
                accA[0][1] = fmaf(wA0, bhi(u[p][0]), accA[0][1]);
                accA[1][0] = fmaf(wA1, blo(u[p][1]), accA[1][0]);
                accA[1][1] = fmaf(wA1, bhi(u[p][1]), accA[1][1]);
                accA[2][0] = fmaf(wA2, blo(u[p][2]), accA[2][0]);
                accA[2][1] = fmaf(wA2, bhi(u[p][2]), accA[2][1]);
                accB[0][0] = fmaf(wB0, blo(u[p][3]), accB[0][0]);
                accB[0][1] = fmaf(wB0, bhi(u[p][3]), accB[0][1]);
                accB[1][0] = fmaf(wB1, blo(u[p][4]), accB[1][0]);
                accB[1][1] = fmaf(wB1, bhi(u[p][4]), accB[1][1]);
                accB[2][0] = fmaf(wB2, blo(u[p][5]), accB[2][0]);
                accB[2][1] = fmaf(wB2, bhi(u[p][5]), accB[2][1]);
            }
        }
        for (; q < cntc; q++) {
            const int sbA = __builtin_amdgcn_readlane(s, q);
            const int sbB = __builtin_amdgcn_readlane(s, 32 + q);
            const unsigned short* hA = h + (size_t)(bt + sbA) * Cc + 2 * lane;
            const unsigned short* hB = h + (size_t)(bt + sbB) * Cc + 2 * lane;
            unsigned int u0 = *(const unsigned int*)(hA);
            unsigned int u1 = *(const unsigned int*)(hA + 128);
            unsigned int u2 = *(const unsigned int*)(hA + 256);
            unsigned int u3 = *(const unsigned int*)(hB);
            unsigned int u4 = *(const unsigned int*)(hB + 128);
            unsigned int u5 = *(const unsigned int*)(hB + 256);
            const int eA = q * 6 + wsel;
            const int eB = eA + 192;
            const float wA0 = exbuf[eA], wA1 = exbuf[eA + 2], wA2 = exbuf[eA + 4];
            const float wB0 = exbuf[eB], wB1 = exbuf[eB + 2], wB2 = exbuf[eB + 4];
            accA[0][0] = fmaf(wA0, blo(u0), accA[0][0]);
            accA[0][1] = fmaf(wA0, bhi(u0), accA[0][1]);
            accA[1][0] = fmaf(wA1, blo(u1), accA[1][0]);
            accA[1][1] = fmaf(wA1, bhi(u1), accA[1][1]);
            accA[2][0] = fmaf(wA2, blo(u2), accA[2][0]);
            accA[2][1] = fmaf(wA2, bhi(u2), accA[2][1]);
            accB[0][0] = fmaf(wB0, blo(u3), accB[0][0]);
            accB[0][1] = fmaf(wB0, bhi(u3), accB[0][1]);
            accB[1][0] = fmaf(wB1, blo(u4), accB[1][0]);
            accB[1][1] = fmaf(wB1, bhi(u4), accB[1][1]);
            accB[2][0] = fmaf(wB2, blo(u5), accB[2][0]);
            accB[2][1] = fmaf(wB2, bhi(u5), accB[2][1]);
        }
    }

    // half-wave den reduce (A in lanes 0-31, B in 32-63)
#pragma unroll
    for (int j = 0; j < 6; j++)
#pragma unroll
        for (int off = 1; off < 32; off <<= 1) den[j] += __shfl_xor(den[j], off);
    float denA[6], denB[6];
#pragma unroll
    for (int j = 0; j < 6; j++) { denA[j] = __shfl(den[j], 0); denB[j] = __shfl(den[j], 32); }

    // epilogue for each node: residual x2 + fused LayerNorm2 -> bf16 xn
#pragma unroll
    for (int nd = 0; nd < 2; nd++) {
        const int gid = nd ? gidB : gidA;
        float2 ov[3];
#pragma unroll
        for (int k = 0; k < 3; k++) {
            float d = nd ? denB[2 * k + wsel] : denA[2 * k + wsel];
            float inv = 1.0f / d;
            float a0 = nd ? accB[k][0] : accA[k][0];
            float a1 = nd ? accB[k][1] : accA[k][1];
            const int chan = k * 128 + 2 * lane;
            const size_t idx = (size_t)gid * Cc + chan;
            const float2 bg = *(const float2*)(bgat + chan);
            const float2 xv = *(const float2*)(x + idx);
            ov[k].x = fmaf(a0, inv, bg.x + xv.x);
            ov[k].y = fmaf(a1, inv, bg.y + xv.y);
            *(float2*)(x2 + idx) = ov[k];
        }
        float sum = 0.f, sq = 0.f;
#pragma unroll
        for (int k = 0; k < 3; k++) {
            sum += ov[k].x + ov[k].y;
            sq += ov[k].x * ov[k].x + ov[k].y * ov[k].y;
        }
#pragma unroll
        for (int off = 1; off < 64; off <<= 1) { sum += __shfl_xor(sum, off); sq += __shfl_xor(sq, off); }
        const float mu = sum * (1.f / 384.f);
        const float var = sq * (1.f / 384.f) - mu * mu;
        const float rs = rsqrtf(var + 1e-5f);
#pragma unroll
        for (int k = 0; k < 3; k++) {
            const int chan = k * 128 + 2 * lane;
            const size_t idx = (size_t)gid * Cc + chan;
            const float2 gg = *(const float2*)(ln2g + chan);
            const float2 bb = *(const float2*)(ln2b + chan);
            float y0 = (ov[k].x - mu) * rs * gg.x + bb.x;
            float y1 = (ov[k].y - mu) * rs * gg.y + bb.y;
            unsigned int pack = (unsigned int)f2bf(y0) | ((unsigned int)f2bf(y1) << 16);
            *(unsigned int*)(xn + idx) = pack;
        }
    }
}

// ---------------- MFMA bf16 GEMM: C[M,N] = A[M,K] @ Bt[N,K]^T ----------------
// PROVEN 128x128 tile, 4 waves (2x2), each wave 4x4 of 16x16x32 MFMA, BK=64 as
// two BK=32 LDS sub-panels, global_load_lds width-16 staging, 3 blocks/CU.
// (BM=256/8-wave variant regressed ~7%: 64KB LDS -> 2 blocks/CU lost the
// cross-block overlap that hides the vmcnt-drain barrier stall.)
// Epilogue: wave-local LDS transpose -> coalesced b128/f32x4 stores.
// EPI: 1 = +bias, relu, store bf16; 2 = +bias +resid, store f32; 3 = store bf16
template <int EPI>
__global__ __launch_bounds__(256, 3) void mfma_gemm(const unsigned short* __restrict__ A,
                                                    const unsigned short* __restrict__ Bt,
                                                    const float* __restrict__ bias,
                                                    const float* __restrict__ resid,
                                                    void* __restrict__ Cout,
                                                    int M, int N, int K) {
    __shared__ unsigned short lds_buf[2 * 128 * 32 * 2];  // 32 KB: staging + epilogue reuse
    unsigned short* Als = lds_buf;
    unsigned short* Bls = lds_buf + 2 * 128 * 32;
    const int tid = threadIdx.x;
    const int wave = tid >> 6, lane = tid & 63;
    const int quad = lane >> 4, l16 = lane & 15;
    const int wm = (wave >> 1) * 64, wn = (wave & 1) * 64;
    const int bm = blockIdx.y, bn = blockIdx.x;

    const int c0 = wave * 2;
    const int rowin = lane >> 2;
    const int kel = (lane & 3) * 8;

    const unsigned short* ga = A + (size_t)(bm * 128 + c0 * 16 + rowin) * K + kel;
    const unsigned short* gb = Bt + (size_t)(bn * 128 + c0 * 16 + rowin) * K + kel;
    unsigned short* la = Als + c0 * 512;
    unsigned short* lb = Bls + c0 * 512;

    f32x4 acc[4][4] = {};

    for (int k0 = 0; k0 < K; k0 += 64) {
        gl_lds16(ga + k0, la);
        gl_lds16(ga + k0 + (size_t)16 * K, la + 512);
        gl_lds16(ga + k0 + 32, la + 4096);
        gl_lds16(ga + k0 + (size_t)16 * K + 32, la + 4096 + 512);
        gl_lds16(gb + k0, lb);
        gl_lds16(gb + k0 + (size_t)16 * K, lb + 512);
        gl_lds16(gb + k0 + 32, lb + 4096);
        gl_lds16(gb + k0 + (size_t)16 * K + 32, lb + 4096 + 512);
        __syncthreads();
#pragma unroll
        for (int hh = 0; hh < 2; hh++) {
            bf16x8 af[4], bfr[4];
#pragma unroll
            for (int i = 0; i < 4; i++) {
                af[i]  = *(const bf16x8*)(Als + hh * 4096 + (wm + i * 16 + l16) * 32 + quad * 8);
                bfr[i] = *(const bf16x8*)(Bls + hh * 4096 + (wn + i * 16 + l16) * 32 + quad * 8);
            }
#pragma unroll
            for (int i = 0; i < 4; i++)
#pragma unroll
                for (int j = 0; j < 4; j++)
                    acc[i][j] = __builtin_amdgcn_mfma_f32_16x16x32_bf16(af[i], bfr[j], acc[i][j], 0, 0, 0);
        }
        __syncthreads();
    }

    // -------- epilogue: wave-local 64x64 LDS transpose -> coalesced stores --------
    const int gr0 = bm * 128 + wm;
    const int gc0 = bn * 128 + wn;

    if constexpr (EPI == 1 || EPI == 3) {
        // bf16 output: wave tile [64][64] shorts = 8 KB, 16B-chunk swizzle chunk^(row&7)
        unsigned short* ep = lds_buf + wave * 4096;
#pragma unroll
        for (int i = 0; i < 4; i++) {
#pragma unroll
            for (int j = 0; j < 4; j++) {
                const int cl = j * 16 + l16;
                const float bv = (EPI == 1) ? bias[gc0 + cl] : 0.f;
#pragma unroll
                for (int r = 0; r < 4; r++) {
                    const int rl = i * 16 + quad * 4 + r;
                    float v = acc[i][j][r] + bv;
                    if constexpr (EPI == 1) v = fmaxf(v, 0.f);
                    ep[rl * 64 + (((cl >> 3) ^ (rl & 7)) << 3) + (cl & 7)] = f2bf(v);
                }
            }
        }
        __syncthreads();
        unsigned short* co = (unsigned short*)Cout;
#pragma unroll
        for (int c = 0; c < 8; c++) {
            const int rl = c * 8 + (lane >> 3);
            const int ch = (lane & 7) ^ (rl & 7);
            bf16x8 vv = *(const bf16x8*)(ep + rl * 64 + ch * 8);
            *(bf16x8*)(co + (size_t)(gr0 + rl) * N + gc0 + (lane & 7) * 8) = vv;
        }
    } else {
        // EPI == 2: f32 output + resid. Two half-passes of [32][64] f32 = 8 KB/wave,
        // 16B-chunk swizzle chunk^(row&15); float4 resid loads + f32x4 stores.
        float* epf = (float*)lds_buf + wave * 2048;
        float* co = (float*)Cout;
#pragma unroll
        for (int hp = 0; hp < 2; hp++) {
            if (hp) __syncthreads();
#pragma unroll
            for (int i2 = 0; i2 < 2; i2++) {
                const int i = hp * 2 + i2;
#pragma unroll
                for (int j = 0; j < 4; j++) {
                    const int cl = j * 16 + l16;
                    const float bv = bias[gc0 + cl];
#pragma unroll
                    for (int r = 0; r < 4; r++) {
                        const int rl = i2 * 16 + quad * 4 + r;
                        epf[rl * 64 + (((cl >> 2) ^ (rl & 15)) << 2) + (cl & 3)] = acc[i][j][r] + bv;
                    }
                }
            }
            __syncthreads();
#pragma unroll
            for (int c = 0; c < 8; c++) {
                const int rl = c * 4 + (lane >> 4);
                const int ch = (lane & 15) ^ (rl & 15);
                f32x4 vv = *(const f32x4*)(epf + rl * 64 + ch * 4);
                const size_t gidx = (size_t)(gr0 + hp * 32 + rl) * N + gc0 + (lane & 15) * 4;
                const f32x4 rr = *(const f32x4*)(resid + gidx);
                vv += rr;
                *(f32x4*)(co + gidx) = vv;
            }
        }
    }
}

extern "C" void kernel_launch(void* const* d_in, const int* in_sizes, int n_in,
                              void* d_out, int out_size, void* d_ws, size_t ws_size,
                              hipStream_t stream) {
    (void)in_sizes; (void)n_in; (void)out_size; (void)ws_size;
    const float* x      = (const float*)d_in[0];
    const int*   ei     = (const int*)d_in[1];
    const float* Wgat   = (const float*)d_in[2];
    const float* attsrc = (const float*)d_in[3];
    const float* attdst = (const float*)d_in[4];
    const float* bgat   = (const float*)d_in[5];
    const float* ln1g   = (const float*)d_in[6];
    const float* ln1b   = (const float*)d_in[7];
    const float* ln2g   = (const float*)d_in[8];
    const float* ln2b   = (const float*)d_in[9];
    const float* W1     = (const float*)d_in[10];
    const float* b1     = (const float*)d_in[11];
    const float* W2     = (const float*)d_in[12];
    const float* b2     = (const float*)d_in[13];
    float* out = (float*)d_out;

    const int* srcp = ei;
    const int* dstp = ei + Ee;

    // workspace layout (all chunks 16B-aligned by construction)
    char* p = (char*)d_ws;
    unsigned short* xn = (unsigned short*)p; p += (size_t)NROWS * Cc * 2;        // LN out, bf16
    unsigned short* h = (unsigned short*)p; p += (size_t)NROWS * Cc * 2;          // GAT features, bf16
    float* asrc = (float*)p; p += (size_t)NROWS * Hh * 4;
    float* adst = (float*)p; p += (size_t)NROWS * Hh * 4;
    unsigned short* ffn1 = (unsigned short*)p; p += (size_t)NROWS * DFF * 2;      // bf16
    unsigned short* wgt = (unsigned short*)p; p += (size_t)Cc * Cc * 2;           // W_gat^T bf16
    unsigned short* w1t = (unsigned short*)p; p += (size_t)DFF * Cc * 2;          // W1^T bf16
    unsigned short* w2t = (unsigned short*)p; p += (size_t)Cc * DFF * 2;          // W2^T bf16
    float* wcomb = (float*)p; p += (size_t)Cc * 12 * 4;                            // folded att weights
    int* rowptr = (int*)p; p += (Tt + 1) * 4;
    int* cursor = (int*)p; p += Tt * 4;
    int* csr = (int*)p; p += (size_t)Ee * 4;

    // weight convert+transpose + folded attention weights (once per launch, tiny)
    transpose_bf16_kernel<<<dim3(Cc / 32, Cc / 32), 256, 0, stream>>>(Wgat, wgt, Cc, Cc);
    transpose_bf16_kernel<<<dim3(DFF / 32, Cc / 32), 256, 0, stream>>>(W1, w1t, Cc, DFF);
    transpose_bf16_kernel<<<dim3(Cc / 32, DFF / 32), 256, 0, stream>>>(W2, w2t, DFF, Cc);
    wcomb_kernel<<<18, 256, 0, stream>>>(Wgat, attsrc, attdst, wcomb);

    // CSR build (batch-independent)
    hipMemsetAsync(cursor, 0, Tt * sizeof(int), stream);
    count_kernel<<<(Ee + 255) / 256, 256, 0, stream>>>(dstp, cursor);
    scan_kernel<<<1, 1024, 0, stream>>>(cursor, rowptr);
    scatter_kernel<<<(Ee + 255) / 256, 256, 0, stream>>>(srcp, dstp, cursor, csr);

    // LN1 -> bf16 xn, fused asrc/adst
    ln1_att_kernel<<<NROWS / 4, 256, 0, stream>>>(x, ln1g, ln1b, wcomb, xn, asrc, adst);
    // h = xn @ W_gat  (bf16 out)
    mfma_gemm<3><<<dim3(Cc / 128, NROWS / 128), 256, 0, stream>>>(
        xn, wgt, nullptr, nullptr, h, NROWS, Cc, Cc);
    // GAT aggregation + bias + residual -> out, fused LN2 -> xn (bf16)
    gat_kernel<<<NROWS / 8, 256, 0, stream>>>(h, asrc, adst, rowptr, csr, x, bgat,
                                              ln2g, ln2b, out, xn);
    // ffn1 = relu(xn @ W1 + b1) -> bf16
    mfma_gemm<1><<<dim3(DFF / 128, NROWS / 128), 256, 0, stream>>>(
        xn, w1t, b1, nullptr, ffn1, NROWS, DFF, Cc);
    // out = ffn1 @ W2 + b2 + out
    mfma_gemm<2><<<dim3(Cc / 128, NROWS / 128), 256, 0, stream>>>(
        ffn1, w2t, b2, out, out, NROWS, Cc, DFF);
}

// Round 8
// 379.282 us; speedup vs baseline: 1.0780x; 1.0629x over previous
//
#include <hip/hip_runtime.h>
#include <hip/hip_bf16.h>

#define Bb 8
#define Tt 4096
#define Cc 384
#define Hh 6
#define Ee 131072
#define DFF 1536
#define NROWS (Bb * Tt)
#define NEG_SLOPE 0.2f

typedef short bf16x8 __attribute__((ext_vector_type(8)));
typedef float f32x4 __attribute__((ext_vector_type(4)));

__device__ inline float bf2f(unsigned short u) {
    union { unsigned int i; float f; } x; x.i = ((unsigned int)u) << 16; return x.f;
}
__device__ inline unsigned short f2bf(float f) {
    union { float f; unsigned int i; } x; x.f = f;
    unsigned int r = x.i + 0x7fffu + ((x.i >> 16) & 1u);
    return (unsigned short)(r >> 16);
}
__device__ __forceinline__ float blo(unsigned int u) {
    union { unsigned int i; float f; } x; x.i = u << 16; return x.f;
}
__device__ __forceinline__ float bhi(unsigned int u) {
    union { unsigned int i; float f; } x; x.i = u & 0xffff0000u; return x.f;
}

__device__ __forceinline__ void gl_lds16(const unsigned short* g, unsigned short* l) {
    __builtin_amdgcn_global_load_lds(
        (const __attribute__((address_space(1))) unsigned int*)g,
        (__attribute__((address_space(3))) unsigned int*)l,
        16, 0, 0);
}

// ---------------- Wcomb[k][j] = sum_f Wgat[k][hd*64+f] * att[hd][f] ----------------
__global__ void wcomb_kernel(const float* __restrict__ Wgat,
                             const float* __restrict__ att_src,
                             const float* __restrict__ att_dst,
                             float* __restrict__ Wcomb) {
    int t = blockIdx.x * 256 + threadIdx.x;
    if (t >= 384 * 12) return;
    int k = t / 12, j = t % 12;
    int hd = j % 6;
    const float* av = (j < 6 ? att_src : att_dst) + hd * 64;
    const float* wr = Wgat + (size_t)k * Cc + hd * 64;
    float acc = 0.f;
#pragma unroll 8
    for (int f = 0; f < 64; f++) acc = fmaf(wr[f], av[f], acc);
    Wcomb[k * 12 + j] = acc;
}

__device__ __forceinline__ void acc_wcomb(float yq, int c, const float* __restrict__ Wcomb,
                                          float* __restrict__ p) {
    const float4* w = (const float4*)(Wcomb + (size_t)c * 12);
    float4 w0 = w[0], w1 = w[1], w2 = w[2];
    p[0] = fmaf(yq, w0.x, p[0]); p[1] = fmaf(yq, w0.y, p[1]);
    p[2] = fmaf(yq, w0.z, p[2]); p[3] = fmaf(yq, w0.w, p[3]);
    p[4] = fmaf(yq, w1.x, p[4]); p[5] = fmaf(yq, w1.y, p[5]);
    p[6] = fmaf(yq, w1.z, p[6]); p[7] = fmaf(yq, w1.w, p[7]);
    p[8] = fmaf(yq, w2.x, p[8]); p[9] = fmaf(yq, w2.y, p[9]);
    p[10] = fmaf(yq, w2.z, p[10]); p[11] = fmaf(yq, w2.w, p[11]);
}

// ---------------- LN1 -> bf16, fused attention logits: one wave per row ----------------
__global__ __launch_bounds__(256) void ln1_att_kernel(const float* __restrict__ x,
                                                      const float* __restrict__ g,
                                                      const float* __restrict__ b,
                                                      const float* __restrict__ Wcomb,
                                                      unsigned short* __restrict__ y,
                                                      float* __restrict__ asrc,
                                                      float* __restrict__ adst) {
    int row = blockIdx.x * 4 + (threadIdx.x >> 6);
    int lane = threadIdx.x & 63;
    const float* xr = x + (size_t)row * Cc;
    const float4 v4 = *(const float4*)(xr + 4 * lane);
    const float2 v1 = *(const float2*)(xr + 256 + 2 * lane);
    float sum = v4.x + v4.y + v4.z + v4.w + v1.x + v1.y;
    float sq = v4.x * v4.x + v4.y * v4.y + v4.z * v4.z + v4.w * v4.w + v1.x * v1.x + v1.y * v1.y;
#pragma unroll
    for (int off = 1; off < 64; off <<= 1) { sum += __shfl_xor(sum, off); sq += __shfl_xor(sq, off); }
    const float mu = sum * (1.f / 384.f);
    const float var = sq * (1.f / 384.f) - mu * mu;
    const float rs = rsqrtf(var + 1e-5f);
    const float4 g4 = *(const float4*)(g + 4 * lane);
    const float4 b4 = *(const float4*)(b + 4 * lane);
    const float2 g1 = *(const float2*)(g + 256 + 2 * lane);
    const float2 b1 = *(const float2*)(b + 256 + 2 * lane);
    float p[12];
#pragma unroll
    for (int jj = 0; jj < 12; jj++) p[jj] = 0.f;
    const int c4 = 4 * lane, c1 = 256 + 2 * lane;
    const unsigned short u0 = f2bf((v4.x - mu) * rs * g4.x + b4.x);
    const unsigned short u1 = f2bf((v4.y - mu) * rs * g4.y + b4.y);
    const unsigned short u2 = f2bf((v4.z - mu) * rs * g4.z + b4.z);
    const unsigned short u3 = f2bf((v4.w - mu) * rs * g4.w + b4.w);
    const unsigned short u4 = f2bf((v1.x - mu) * rs * g1.x + b1.x);
    const unsigned short u5 = f2bf((v1.y - mu) * rs * g1.y + b1.y);
    acc_wcomb(bf2f(u0), c4 + 0, Wcomb, p);
    acc_wcomb(bf2f(u1), c4 + 1, Wcomb, p);
    acc_wcomb(bf2f(u2), c4 + 2, Wcomb, p);
    acc_wcomb(bf2f(u3), c4 + 3, Wcomb, p);
    acc_wcomb(bf2f(u4), c1 + 0, Wcomb, p);
    acc_wcomb(bf2f(u5), c1 + 1, Wcomb, p);
    unsigned short* yr = y + (size_t)row * Cc;
    uint2 pk4;
    pk4.x = (unsigned int)u0 | ((unsigned int)u1 << 16);
    pk4.y = (unsigned int)u2 | ((unsigned int)u3 << 16);
    *(uint2*)(yr + c4) = pk4;
    *(unsigned int*)(yr + c1) = (unsigned int)u4 | ((unsigned int)u5 << 16);
#pragma unroll
    for (int off = 1; off < 64; off <<= 1)
#pragma unroll
        for (int jj = 0; jj < 12; jj++) p[jj] += __shfl_xor(p[jj], off);
    if (lane == 0) {
        float* as_ = asrc + row * Hh;
        float* ad_ = adst + row * Hh;
        as_[0] = p[0]; as_[1] = p[1]; as_[2] = p[2];
        as_[3] = p[3]; as_[4] = p[4]; as_[5] = p[5];
        ad_[0] = p[6]; ad_[1] = p[7]; ad_[2] = p[8];
        ad_[3] = p[9]; ad_[4] = p[10]; ad_[5] = p[11];
    }
}

// ---------------- W [K][N] f32 -> Wt [N][K] bf16 (32x32 LDS transpose) ----------------
__global__ __launch_bounds__(256) void transpose_bf16_kernel(const float* __restrict__ W,
                                                             unsigned short* __restrict__ Wt,
                                                             int K, int N) {
    __shared__ float t[32][33];
    const int n0 = blockIdx.x * 32, k0 = blockIdx.y * 32;
    const int tx = threadIdx.x & 31, ty = threadIdx.x >> 5;  // 32 x 8
#pragma unroll
    for (int dy = 0; dy < 32; dy += 8)
        t[ty + dy][tx] = W[(size_t)(k0 + ty + dy) * N + n0 + tx];
    __syncthreads();
#pragma unroll
    for (int dy = 0; dy < 32; dy += 8)
        Wt[(size_t)(n0 + ty + dy) * K + k0 + tx] = f2bf(t[tx][ty + dy]);
}

// ---------------- CSR build ----------------
__global__ void count_kernel(const int* __restrict__ dst, int* __restrict__ deg) {
    int e = blockIdx.x * 256 + threadIdx.x;
    if (e < Ee) atomicAdd(&deg[dst[e]], 1);
}

// Wave-level shfl scan (no barriers) + 16-entry cross-wave scan (2 barriers).
__global__ __launch_bounds__(1024) void scan_kernel(int* __restrict__ deg_cursor,
                                                    int* __restrict__ rowptr) {
    __shared__ int wsum[16];
    const int tid = threadIdx.x;
    const int lane = tid & 63;
    const int wv = tid >> 6;
    const int base_i = tid * 4;
    int v[4];
#pragma unroll
    for (int i = 0; i < 4; i++) v[i] = deg_cursor[base_i + i];
    const int s = v[0] + v[1] + v[2] + v[3];
    int incl = s;  // inclusive scan within wave
#pragma unroll
    for (int off = 1; off < 64; off <<= 1) {
        int t = __shfl_up(incl, off);
        if (lane >= off) incl += t;
    }
    if (lane == 63) wsum[wv] = incl;
    __syncthreads();
    if (tid < 16) {
        int ws = wsum[tid];
#pragma unroll
        for (int off = 1; off < 16; off <<= 1) {
            int t = __shfl_up(ws, off, 16);
            if (tid >= off) ws += t;
        }
        wsum[tid] = ws;  // inclusive wave-prefix
    }
    __syncthreads();
    const int wave_excl = (wv == 0) ? 0 : wsum[wv - 1];
    int r = wave_excl + incl - s;  // exclusive prefix for this thread
#pragma unroll
    for (int i = 0; i < 4; i++) { rowptr[base_i + i] = r; deg_cursor[base_i + i] = r; r += v[i]; }
    if (tid == 0) rowptr[Tt] = wsum[15];
}

__global__ void scatter_kernel(const int* __restrict__ src, const int* __restrict__ dst,
                               int* __restrict__ cursor, int* __restrict__ csr) {
    int e = blockIdx.x * 256 + threadIdx.x;
    if (e < Ee) {
        int d = dst[e];
        int pos = atomicAdd(&cursor[d], 1);
        csr[pos] = src[e];
    }
}

// ---------------- GAT aggregation + fused LN2: TWO nodes per wave ----------------
// R5-EXACT revert (76.9 us proven): x8 gather batch + __launch_bounds__(256,2).
// Tuning series closed: VGPR48/occ42% -> 93us+, VGPR64/occ34% -> 76.9us (best),
// VGPR72/occ26% (waves_per_eu(2,3)) -> 81.5us. Occupancy beats per-wave ILP here.
// XCD-aware batch partitioning: batch = blockIdx.x & 7 (h slice fits XCD L2).
__global__ __launch_bounds__(256, 2) void gat_kernel(const unsigned short* __restrict__ h,
                                                     const float* __restrict__ asrc,
                                                     const float* __restrict__ adst,
                                                     const int* __restrict__ rowptr,
                                                     const int* __restrict__ csr,
                                                     const float* __restrict__ x,
                                                     const float* __restrict__ bgat,
                                                     const float* __restrict__ ln2g,
                                                     const float* __restrict__ ln2b,
                                                     float* __restrict__ x2,
                                                     unsigned short* __restrict__ xn) {
    __shared__ float lds_ex[4][64 * 6];
    const int wave = threadIdx.x >> 6;
    const int lane = threadIdx.x & 63;
    const int batch = blockIdx.x & 7;                 // XCD id (blockIdx%8 round-robin)
    const int pairi = (blockIdx.x >> 3) * 4 + wave;   // within-batch pair index 0..2047
    const int gidA = batch * Tt + pairi * 2;
    const int gidB = gidA + 1;
    const int bt = batch * Tt;
    const int tA = pairi * 2;
    const int halflane = lane & 31;
    const bool isB = lane >= 32;
    const bool hihalf = isB;
    const int wsel = hihalf ? 1 : 0;
    float* exbuf = lds_ex[wave];

    // adst for both nodes (wave-uniform)
    float adA[6], adB[6];
    {
        const float2* pA = (const float2*)(adst + gidA * Hh);
        const float2* pB = (const float2*)(adst + gidB * Hh);
        float2 a0 = pA[0], a1 = pA[1], a2 = pA[2];
        float2 b0 = pB[0], b1 = pB[1], b2 = pB[2];
        adA[0] = a0.x; adA[1] = a0.y; adA[2] = a1.x; adA[3] = a1.y; adA[4] = a2.x; adA[5] = a2.y;
        adB[0] = b0.x; adB[1] = b0.y; adB[2] = b1.x; adB[3] = b1.y; adB[4] = b2.x; adB[5] = b2.y;
    }
    // self-loop exp weights
    float exsA[6], exsB[6];
    {
        const float2* pA = (const float2*)(asrc + gidA * Hh);
        const float2* pB = (const float2*)(asrc + gidB * Hh);
        float2 a0 = pA[0], a1 = pA[1], a2 = pA[2];
        float2 b0 = pB[0], b1 = pB[1], b2 = pB[2];
        float sA[6] = {a0.x, a0.y, a1.x, a1.y, a2.x, a2.y};
        float sB[6] = {b0.x, b0.y, b1.x, b1.y, b2.x, b2.y};
#pragma unroll
        for (int j = 0; j < 6; j++) {
            float a = sA[j] + adA[j];
            a = (a >= 0.f) ? a : NEG_SLOPE * a;
            exsA[j] = __expf(a);
            float c = sB[j] + adB[j];
            c = (c >= 0.f) ? c : NEG_SLOPE * c;
            exsB[j] = __expf(c);
        }
    }
    float den[6];
#pragma unroll
    for (int j = 0; j < 6; j++)
        den[j] = (lane == 0) ? exsA[j] : ((lane == 32) ? exsB[j] : 0.f);

    float accA[3][2], accB[3][2];
    {
        const unsigned short* hA = h + (size_t)gidA * Cc + 2 * lane;
        const unsigned short* hB = h + (size_t)gidB * Cc + 2 * lane;
#pragma unroll
        for (int k = 0; k < 3; k++) {
            unsigned int uA = *(const unsigned int*)(hA + k * 128);
            unsigned int uB = *(const unsigned int*)(hB + k * 128);
            float wA = exsA[2 * k + wsel];
            float wB = exsB[2 * k + wsel];
            accA[k][0] = wA * blo(uA); accA[k][1] = wA * bhi(uA);
            accB[k][0] = wB * blo(uB); accB[k][1] = wB * bhi(uB);
        }
    }

    const int e0A = rowptr[tA], e1A = rowptr[tA + 1], e1B = rowptr[tA + 2];
    const int e0B = e1A;
    const int cntA = e1A - e0A, cntB = e1B - e0B;
    const int maxcnt = cntA > cntB ? cntA : cntB;
    const int my_e0 = isB ? e0B : e0A;
    const int my_e1 = isB ? e1B : e1A;
    float adM[6];
#pragma unroll
    for (int j = 0; j < 6; j++) adM[j] = isB ? adB[j] : adA[j];

    for (int c = 0; c < maxcnt; c += 32) {
        const int e = my_e0 + c + halflane;
        const bool valid = e < my_e1;
        int eidx = valid ? e : (my_e1 - 1);
        eidx = eidx < 0 ? 0 : eidx;
        const int s = csr[eidx];
        const int nb = bt + s;
        float ex[6];
        {
            const float2* ap = (const float2*)(asrc + nb * Hh);
            float2 a01 = ap[0], a23 = ap[1], a45 = ap[2];
            float al[6] = {a01.x, a01.y, a23.x, a23.y, a45.x, a45.y};
#pragma unroll
            for (int j = 0; j < 6; j++) {
                float a = al[j] + adM[j];
                a = (a >= 0.f) ? a : NEG_SLOPE * a;
                float exx = __expf(a);
                ex[j] = valid ? exx : 0.f;
                den[j] += ex[j];
            }
        }
        *(float2*)&exbuf[lane * 6 + 0] = make_float2(ex[0], ex[1]);
        *(float2*)&exbuf[lane * 6 + 2] = make_float2(ex[2], ex[3]);
        *(float2*)&exbuf[lane * 6 + 4] = make_float2(ex[4], ex[5]);

        const int rem = maxcnt - c;
        const int cntc = rem < 32 ? rem : 32;
        int q = 0;
        // x8 batch: 48 dwords in flight (needs the (256,2) VGPR allowance)
        for (; q + 8 <= cntc; q += 8) {
            unsigned int u[8][6];
#pragma unroll
            for (int p = 0; p < 8; p++) {
                const int sbA = __builtin_amdgcn_readlane(s, q + p);
                const int sbB = __builtin_amdgcn_readlane(s, 32 + q + p);
                const unsigned short* hA = h + (size_t)(bt + sbA) * Cc + 2 * lane;
                const unsigned short* hB = h + (size_t)(bt + sbB) * Cc + 2 * lane;
                u[p][0] = *(const unsigned int*)(hA);
                u[p][1] = *(const unsigned int*)(hA + 128);
                u[p][2] = *(const unsigned int*)(hA + 256);
                u[p][3] = *(const unsigned int*)(hB);
                u[p][4] = *(const unsigned int*)(hB + 128);
                u[p][5] = *(const unsigned int*)(hB + 256);
            }
#pragma unroll
            for (int p = 0; p < 8; p++) {
                const int eA = (q + p) * 6 + wsel;
                const int eB = eA + 192;
                const float wA0 = exbuf[eA], wA1 = exbuf[eA + 2], wA2 = exbuf[eA + 4];
                const float wB0 = exbuf[eB], wB1 = exbuf[eB + 2], wB2 = exbuf[eB + 4];
                accA[0][0] = fmaf(wA0, blo(u[p][0]), accA[0][0]);
                accA[0][1] = fmaf(wA0, bhi(u[p][0]), accA[0][1]);
                accA[1][0] = fmaf(wA1, blo(u[p][1]), accA[1][0]);
                accA[1][1] = fmaf(wA1, bhi(u[p][1]), accA[1][1]);
                accA[2][0] = fmaf(wA2, blo(u[p][2]), accA[2][0]);
                accA[2][1] = fmaf(wA2, bhi(u[p][2]), accA[2][1]);
                accB[0][0] = fmaf(wB0, blo(u[p][3]), accB[0][0]);
                accB[0][1] = fmaf(wB0, bhi(u[p][3]), accB[0][1]);
                accB[1][0] = fmaf(wB1, blo(u[p][4]), accB[1][0]);
                accB[1][1] = fmaf(wB1, bhi(u[p][4]), accB[1][1]);
                accB[2][0] = fmaf(wB2, blo(u[p][5]), accB[2][0]);
                accB[2][1] = fmaf(wB2, bhi(u[p][5]), accB[2][1]);
            }
        }
        for (; q + 4 <= cntc; q += 4) {
            unsigned int u[4][6];
#pragma unroll
            for (int p = 0; p < 4; p++) {
                const int sbA = __builtin_amdgcn_readlane(s, q + p);
                const int sbB = __builtin_amdgcn_readlane(s, 32 + q + p);
                const unsigned short* hA = h + (size_t)(bt + sbA) * Cc + 2 * lane;
                const unsigned short* hB = h + (size_t)(bt + sbB) * Cc + 2 * lane;
                u[p][0] = *(const unsigned int*)(hA);
                u[p][1] = *(const unsigned int*)(hA + 128);
                u[p][2] = *(const unsigned int*)(hA + 256);
                u[p][3] = *(const unsigned int*)(hB);
                u[p][4] = *(const unsigned int*)(hB + 128);
                u[p][5] = *(const unsigned int*)(hB + 256);
            }
#pragma unroll
            for (int p = 0; p < 4; p++) {
                const int eA = (q + p) * 6 + wsel;
                const int eB = eA + 192;
                const float wA0 = exbuf[eA], wA1 = exbuf[eA + 2], wA2 = exbuf[eA + 4];
                const float wB0 = exbuf[eB], wB1 = exbuf[eB + 2], wB2 = exbuf[eB + 4];
                accA[0][0] = fmaf(wA0, blo(u[p][0]), accA[0][0]);
                accA[0][1] = fmaf(wA0, bhi(u[p][0]), accA[0][1]);
                accA[1][0] = fmaf(wA1, blo(u[p][1]), accA[1][0]);
                accA[1][1] = fmaf(wA1, bhi(u[p][1]), accA[1][1]);
                accA[2][0] = fmaf(wA2, blo(u[p][2]), accA[2][0]);
                accA[2][1] = fmaf(wA2, bhi(u[p][2]), accA[2][1]);
                accB[0][0] = fmaf(wB0, blo(u[p][3]), accB[0][0]);
                accB[0][1] = fmaf(wB0, bhi(u[p][3]), accB[0][1]);
                accB[1][0] = fmaf(wB1, blo(u[p][4]), accB[1][0]);
                accB[1][1] = fmaf(wB1, bhi(u[p][4]), accB[1][1]);
                accB[2][0] = fmaf(wB2, blo(u[p][5]), accB[2][0]);
                accB[2][1] = fmaf(wB2, bhi(u[p][5]), accB[2][1]);
            }
        }
        for (; q < cntc; q++) {
            const int sbA = __builtin_amdgcn_readlane(s, q);
            const int sbB = __builtin_amdgcn_readlane(s, 32 + q);
            const unsigned short* hA = h + (size_t)(bt + sbA) * Cc + 2 * lane;
            const unsigned short* hB = h + (size_t)(bt + sbB) * Cc + 2 * lane;
            unsigned int u0 = *(const unsigned int*)(hA);
            unsigned int u1 = *(const unsigned int*)(hA + 128);
            unsigned int u2 = *(const unsigned int*)(hA + 256);
            unsigned int u3 = *(const unsigned int*)(hB);
            unsigned int u4 = *(const unsigned int*)(hB + 128);
            unsigned int u5 = *(const unsigned int*)(hB + 256);
            const int eA = q * 6 + wsel;
            const int eB = eA + 192;
            const float wA0 = exbuf[eA], wA1 = exbuf[eA + 2], wA2 = exbuf[eA + 4];
            const float wB0 = exbuf[eB], wB1 = exbuf[eB + 2], wB2 = exbuf[eB + 4];
            accA[0][0] = fmaf(wA0, blo(u0), accA[0][0]);
            accA[0][1] = fmaf(wA0, bhi(u0), accA[0][1]);
            accA[1][0] = fmaf(wA1, blo(u1), accA[1][0]);
            accA[1][1] = fmaf(wA1, bhi(u1), accA[1][1]);
            accA[2][0] = fmaf(wA2, blo(u2), accA[2][0]);
            accA[2][1] = fmaf(wA2, bhi(u2), accA[2][1]);
            accB[0][0] = fmaf(wB0, blo(u3), accB[0][0]);
            accB[0][1] = fmaf(wB0, bhi(u3), accB[0][1]);
            accB[1][0] = fmaf(wB1, blo(u4), accB[1][0]);
            accB[1][1] = fmaf(wB1, bhi(u4), accB[1][1]);
            accB[2][0] = fmaf(wB2, blo(u5), accB[2][0]);
            accB[2][1] = fmaf(wB2, bhi(u5), accB[2][1]);
        }
    }

    // half-wave den reduce (A in lanes 0-31, B in 32-63)
#pragma unroll
    for (int j = 0; j < 6; j++)
#pragma unroll
        for (int off = 1; off < 32; off <<= 1) den[j] += __shfl_xor(den[j], off);
    float denA[6], denB[6];
#pragma unroll
    for (int j = 0; j < 6; j++) { denA[j] = __shfl(den[j], 0); denB[j] = __shfl(den[j], 32); }

    // epilogue for each node: residual x2 + fused LayerNorm2 -> bf16 xn
#pragma unroll
    for (int nd = 0; nd < 2; nd++) {
        const int gid = nd ? gidB : gidA;
        float2 ov[3];
#pragma unroll
        for (int k = 0; k < 3; k++) {
            float d = nd ? denB[2 * k + wsel] : denA[2 * k + wsel];
            float inv = 1.0f / d;
            float a0 = nd ? accB[k][0] : accA[k][0];
            float a1 = nd ? accB[k][1] : accA[k][1];
            const int chan = k * 128 + 2 * lane;
            const size_t idx = (size_t)gid * Cc + chan;
            const float2 bg = *(const float2*)(bgat + chan);
            const float2 xv = *(const float2*)(x + idx);
            ov[k].x = fmaf(a0, inv, bg.x + xv.x);
            ov[k].y = fmaf(a1, inv, bg.y + xv.y);
            *(float2*)(x2 + idx) = ov[k];
        }
        float sum = 0.f, sq = 0.f;
#pragma unroll
        for (int k = 0; k < 3; k++) {
            sum += ov[k].x + ov[k].y;
            sq += ov[k].x * ov[k].x + ov[k].y * ov[k].y;
        }
#pragma unroll
        for (int off = 1; off < 64; off <<= 1) { sum += __shfl_xor(sum, off); sq += __shfl_xor(sq, off); }
        const float mu = sum * (1.f / 384.f);
        const float var = sq * (1.f / 384.f) - mu * mu;
        const float rs = rsqrtf(var + 1e-5f);
#pragma unroll
        for (int k = 0; k < 3; k++) {
            const int chan = k * 128 + 2 * lane;
            const size_t idx = (size_t)gid * Cc + chan;
            const float2 gg = *(const float2*)(ln2g + chan);
            const float2 bb = *(const float2*)(ln2b + chan);
            float y0 = (ov[k].x - mu) * rs * gg.x + bb.x;
            float y1 = (ov[k].y - mu) * rs * gg.y + bb.y;
            unsigned int pack = (unsigned int)f2bf(y0) | ((unsigned int)f2bf(y1) << 16);
            *(unsigned int*)(xn + idx) = pack;
        }
    }
}

// ---------------- MFMA bf16 GEMM: C[M,N] = A[M,K] @ Bt[N,K]^T ----------------
// PROVEN 128x128 tile, 4 waves (2x2), each wave 4x4 of 16x16x32 MFMA, BK=64 as
// two BK=32 LDS sub-panels, global_load_lds width-16 staging, 3 blocks/CU.
// NEW (T1): bijective XCD swizzle of the block id -> each XCD gets a contiguous
// bm chunk (A slice 3 MB fits the 4 MiB per-XCD L2; all bn for those rows on
// one XCD). K=384 = only 6 K-steps/block, so the vmcnt(0)-drain latency per
// step dominates; serving A re-reads from local L2 (~200cy) instead of L3
// (~400-500cy) shortens the drain. Valid: all grids have nwg % 8 == 0.
// EPI: 1 = +bias, relu, store bf16; 2 = +bias +resid, store f32; 3 = store bf16
template <int EPI>
__global__ __launch_bounds__(256, 3) void mfma_gemm(const unsigned short* __restrict__ A,
                                                    const unsigned short* __restrict__ Bt,
                                                    const float* __restrict__ bias,
                                                    const float* __restrict__ resid,
                                                    void* __restrict__ Cout,
                                                    int M, int N, int K) {
    __shared__ unsigned short lds_buf[2 * 128 * 32 * 2];  // 32 KB: staging + epilogue reuse
    unsigned short* Als = lds_buf;
    unsigned short* Bls = lds_buf + 2 * 128 * 32;
    const int tid = threadIdx.x;
    const int wave = tid >> 6, lane = tid & 63;
    const int quad = lane >> 4, l16 = lane & 15;
    const int wm = (wave >> 1) * 64, wn = (wave & 1) * 64;

    // T1 XCD swizzle: wg%8 = XCD (HW round-robin); give each XCD a contiguous
    // linear-id chunk -> contiguous bm range (requires nwg%8==0: 768/3072 ok)
    const int wg = blockIdx.y * gridDim.x + blockIdx.x;
    const int cpx = (gridDim.x * gridDim.y) >> 3;
    const int ln = (wg & 7) * cpx + (wg >> 3);
    const int bn = ln % gridDim.x;
    const int bm = ln / gridDim.x;

    const int c0 = wave * 2;
    const int rowin = lane >> 2;
    const int kel = (lane & 3) * 8;

    const unsigned short* ga = A + (size_t)(bm * 128 + c0 * 16 + rowin) * K + kel;
    const unsigned short* gb = Bt + (size_t)(bn * 128 + c0 * 16 + rowin) * K + kel;
    unsigned short* la = Als + c0 * 512;
    unsigned short* lb = Bls + c0 * 512;

    f32x4 acc[4][4] = {};

    for (int k0 = 0; k0 < K; k0 += 64) {
        gl_lds16(ga + k0, la);
        gl_lds16(ga + k0 + (size_t)16 * K, la + 512);
        gl_lds16(ga + k0 + 32, la + 4096);
        gl_lds16(ga + k0 + (size_t)16 * K + 32, la + 4096 + 512);
        gl_lds16(gb + k0, lb);
        gl_lds16(gb + k0 + (size_t)16 * K, lb + 512);
        gl_lds16(gb + k0 + 32, lb + 4096);
        gl_lds16(gb + k0 + (size_t)16 * K + 32, lb + 4096 + 512);
        __syncthreads();
#pragma unroll
        for (int hh = 0; hh < 2; hh++) {
            bf16x8 af[4], bfr[4];
#pragma unroll
            for (int i = 0; i < 4; i++) {
                af[i]  = *(const bf16x8*)(Als + hh * 4096 + (wm + i * 16 + l16) * 32 + quad * 8);
                bfr[i] = *(const bf16x8*)(Bls + hh * 4096 + (wn + i * 16 + l16) * 32 + quad * 8);
            }
#pragma unroll
            for (int i = 0; i < 4; i++)
#pragma unroll
                for (int j = 0; j < 4; j++)
                    acc[i][j] = __builtin_amdgcn_mfma_f32_16x16x32_bf16(af[i], bfr[j], acc[i][j], 0, 0, 0);
        }
        __syncthreads();
    }

    // -------- epilogue: wave-local 64x64 LDS transpose -> coalesced stores --------
    const int gr0 = bm * 128 + wm;
    const int gc0 = bn * 128 + wn;

    if constexpr (EPI == 1 || EPI == 3) {
        // bf16 output: wave tile [64][64] shorts = 8 KB, 16B-chunk swizzle chunk^(row&7)
        unsigned short* ep = lds_buf + wave * 4096;
#pragma unroll
        for (int i = 0; i < 4; i++) {
#pragma unroll
            for (int j = 0; j < 4; j++) {
                const int cl = j * 16 + l16;
                const float bv = (EPI == 1) ? bias[gc0 + cl] : 0.f;
#pragma unroll
                for (int r = 0; r < 4; r++) {
                    const int rl = i * 16 + quad * 4 + r;
                    float v = acc[i][j][r] + bv;
                    if constexpr (EPI == 1) v = fmaxf(v, 0.f);
                    ep[rl * 64 + (((cl >> 3) ^ (rl & 7)) << 3) + (cl & 7)] = f2bf(v);
                }
            }
        }
        __syncthreads();
        unsigned short* co = (unsigned short*)Cout;
#pragma unroll
        for (int c = 0; c < 8; c++) {
            const int rl = c * 8 + (lane >> 3);
            const int ch = (lane & 7) ^ (rl & 7);
            bf16x8 vv = *(const bf16x8*)(ep + rl * 64 + ch * 8);
            *(bf16x8*)(co + (size_t)(gr0 + rl) * N + gc0 + (lane & 7) * 8) = vv;
        }
    } else {
        // EPI == 2: f32 output + resid. Two half-passes of [32][64] f32 = 8 KB/wave,
        // 16B-chunk swizzle chunk^(row&15); float4 resid loads + f32x4 stores.
        float* epf = (float*)lds_buf + wave * 2048;
        float* co = (float*)Cout;
#pragma unroll
        for (int hp = 0; hp < 2; hp++) {
            if (hp) __syncthreads();
#pragma unroll
            for (int i2 = 0; i2 < 2; i2++) {
                const int i = hp * 2 + i2;
#pragma unroll
                for (int j = 0; j < 4; j++) {
                    const int cl = j * 16 + l16;
                    const float bv = bias[gc0 + cl];
#pragma unroll
                    for (int r = 0; r < 4; r++) {
                        const int rl = i2 * 16 + quad * 4 + r;
                        epf[rl * 64 + (((cl >> 2) ^ (rl & 15)) << 2) + (cl & 3)] = acc[i][j][r] + bv;
                    }
                }
            }
            __syncthreads();
#pragma unroll
            for (int c = 0; c < 8; c++) {
                const int rl = c * 4 + (lane >> 4);
                const int ch = (lane & 15) ^ (rl & 15);
                f32x4 vv = *(const f32x4*)(epf + rl * 64 + ch * 4);
                const size_t gidx = (size_t)(gr0 + hp * 32 + rl) * N + gc0 + (lane & 15) * 4;
                const f32x4 rr = *(const f32x4*)(resid + gidx);
                vv += rr;
                *(f32x4*)(co + gidx) = vv;
            }
        }
    }
}

extern "C" void kernel_launch(void* const* d_in, const int* in_sizes, int n_in,
                              void* d_out, int out_size, void* d_ws, size_t ws_size,
                              hipStream_t stream) {
    (void)in_sizes; (void)n_in; (void)out_size; (void)ws_size;
    const float* x      = (const float*)d_in[0];
    const int*   ei     = (const int*)d_in[1];
    const float* Wgat   = (const float*)d_in[2];
    const float* attsrc = (const float*)d_in[3];
    const float* attdst = (const float*)d_in[4];
    const float* bgat   = (const float*)d_in[5];
    const float* ln1g   = (const float*)d_in[6];
    const float* ln1b   = (const float*)d_in[7];
    const float* ln2g   = (const float*)d_in[8];
    const float* ln2b   = (const float*)d_in[9];
    const float* W1     = (const float*)d_in[10];
    const float* b1     = (const float*)d_in[11];
    const float* W2     = (const float*)d_in[12];
    const float* b2     = (const float*)d_in[13];
    float* out = (float*)d_out;

    const int* srcp = ei;
    const int* dstp = ei + Ee;

    // workspace layout (all chunks 16B-aligned by construction)
    char* p = (char*)d_ws;
    unsigned short* xn = (unsigned short*)p; p += (size_t)NROWS * Cc * 2;        // LN out, bf16
    unsigned short* h = (unsigned short*)p; p += (size_t)NROWS * Cc * 2;          // GAT features, bf16
    float* asrc = (float*)p; p += (size_t)NROWS * Hh * 4;
    float* adst = (float*)p; p += (size_t)NROWS * Hh * 4;
    unsigned short* ffn1 = (unsigned short*)p; p += (size_t)NROWS * DFF * 2;      // bf16
    unsigned short* wgt = (unsigned short*)p; p += (size_t)Cc * Cc * 2;           // W_gat^T bf16
    unsigned short* w1t = (unsigned short*)p; p += (size_t)DFF * Cc * 2;          // W1^T bf16
    unsigned short* w2t = (unsigned short*)p; p += (size_t)Cc * DFF * 2;          // W2^T bf16
    float* wcomb = (float*)p; p += (size_t)Cc * 12 * 4;                            // folded att weights
    int* rowptr = (int*)p; p += (Tt + 1) * 4;
    int* cursor = (int*)p; p += Tt * 4;
    int* csr = (int*)p; p += (size_t)Ee * 4;

    // weight convert+transpose + folded attention weights (once per launch, tiny)
    transpose_bf16_kernel<<<dim3(Cc / 32, Cc / 32), 256, 0, stream>>>(Wgat, wgt, Cc, Cc);
    transpose_bf16_kernel<<<dim3(DFF / 32, Cc / 32), 256, 0, stream>>>(W1, w1t, Cc, DFF);
    transpose_bf16_kernel<<<dim3(Cc / 32, DFF / 32), 256, 0, stream>>>(W2, w2t, DFF, Cc);
    wcomb_kernel<<<18, 256, 0, stream>>>(Wgat, attsrc, attdst, wcomb);

    // CSR build (batch-independent)
    hipMemsetAsync(cursor, 0, Tt * sizeof(int), stream);
    count_kernel<<<(Ee + 255) / 256, 256, 0, stream>>>(dstp, cursor);
    scan_kernel<<<1, 1024, 0, stream>>>(cursor, rowptr);
    scatter_kernel<<<(Ee + 255) / 256, 256, 0, stream>>>(srcp, dstp, cursor, csr);

    // LN1 -> bf16 xn, fused asrc/adst
    ln1_att_kernel<<<NROWS / 4, 256, 0, stream>>>(x, ln1g, ln1b, wcomb, xn, asrc, adst);
    // h = xn @ W_gat  (bf16 out)
    mfma_gemm<3><<<dim3(Cc / 128, NROWS / 128), 256, 0, stream>>>(
        xn, wgt, nullptr, nullptr, h, NROWS, Cc, Cc);
    // GAT aggregation + bias + residual -> out, fused LN2 -> xn (bf16)
    gat_kernel<<<NROWS / 8, 256, 0, stream>>>(h, asrc, adst, rowptr, csr, x, bgat,
                                              ln2g, ln2b, out, xn);
    // ffn1 = relu(xn @ W1 + b1) -> bf16
    mfma_gemm<1><<<dim3(DFF / 128, NROWS / 128), 256, 0, stream>>>(
        xn, w1t, b1, nullptr, ffn1, NROWS, DFF, Cc);
    // out = ffn1 @ W2 + b2 + out
    mfma_gemm<2><<<dim3(Cc / 128, NROWS / 128), 256, 0, stream>>>(
        ffn1, w2t, b2, out, out, NROWS, Cc, DFF);
}